// Round 7
// baseline (398.946 us; speedup 1.0000x reference)
//
#include <hip/hip_runtime.h>

typedef unsigned short u16;
typedef __attribute__((ext_vector_type(4))) unsigned short u16x4;
typedef __attribute__((ext_vector_type(8))) unsigned short u16x8;
typedef __attribute__((ext_vector_type(8))) short s16x8;
typedef __attribute__((ext_vector_type(4))) float f32x4;

__device__ __forceinline__ u16 f2bf(float f) {
  unsigned int u = __float_as_uint(f);
  u += 0x7FFFu + ((u >> 16) & 1u);   // RNE
  return (u16)(u >> 16);
}
__device__ __forceinline__ float bf2f(u16 h) {
  return __uint_as_float(((unsigned int)h) << 16);
}

// async global->LDS, 16B per lane; base = lane0's lds ptr, lane i writes base+i*16B.
__device__ __forceinline__ void gload_lds16(const u16* g, u16* l) {
  __builtin_amdgcn_global_load_lds(
      (const __attribute__((address_space(1))) unsigned int*)(g),
      (__attribute__((address_space(3))) unsigned int*)(l), 16, 0, 0);
}

// ---------------- fp32 -> bf16 convert (x4 vectorized) ----------------
__global__ __launch_bounds__(256) void cvt_kernel(const float* __restrict__ src,
                                                  u16* __restrict__ dst, int n4) {
  int i = blockIdx.x * 256 + threadIdx.x;
  if (i >= n4) return;
  float4 v = reinterpret_cast<const float4*>(src)[i];
  u16x4 o;
  o.x = f2bf(v.x); o.y = f2bf(v.y); o.z = f2bf(v.z); o.w = f2bf(v.w);
  reinterpret_cast<u16x4*>(dst)[i] = o;
}

// all four 1024x1024 weights in one launch
__global__ __launch_bounds__(256) void cvt_w(const float* __restrict__ Wq,
                                             const float* __restrict__ Wk,
                                             const float* __restrict__ Wv,
                                             const float* __restrict__ Wo,
                                             u16* __restrict__ wbf, u16* __restrict__ wobf) {
  int blk = blockIdx.x;           // 0..4095
  int sel = blk >> 10;
  const float* src = (sel == 0) ? Wq : (sel == 1) ? Wk : (sel == 2) ? Wv : Wo;
  u16* dst = (sel < 3) ? (wbf + (size_t)sel * 1048576) : wobf;
  int i = (blk & 1023) * 256 + threadIdx.x;
  float4 v = reinterpret_cast<const float4*>(src)[i];
  u16x4 o;
  o.x = f2bf(v.x); o.y = f2bf(v.y); o.z = f2bf(v.z); o.w = f2bf(v.w);
  reinterpret_cast<u16x4*>(dst)[i] = o;
}

// ---------------- GEMM: C[m][n] = sum_k A[m][k] * B[n][k] (B^T input) ----------------
// 128x128 tile, BK=32, global_load_lds staging, chunk = 16 rows x 32 cols = 512 u16.
__device__ __forceinline__ void store_out(float* p, float v) { *p = v; }
__device__ __forceinline__ void store_out(u16* p, float v) { *p = f2bf(v); }

template <typename OutT>
__global__ __launch_bounds__(256) void gemm_bt(const u16* __restrict__ A,
                                               const u16* __restrict__ Bw,
                                               OutT* __restrict__ C, int N, int K) {
  __shared__ u16 As[4096];
  __shared__ u16 Bs[4096];
  const int tid = threadIdx.x;
  const int lane = tid & 63;
  const int wave = tid >> 6;
  const int wm = wave >> 1, wn = wave & 1;
  const int lh = lane & 15, quad = lane >> 4;
  const int q8 = quad * 8;
  const int m0 = blockIdx.y * 128, n0 = blockIdx.x * 128;

  f32x4 acc[4][4];
#pragma unroll
  for (int i = 0; i < 4; ++i)
#pragma unroll
    for (int j = 0; j < 4; ++j) { acc[i][j][0] = 0.f; acc[i][j][1] = 0.f; acc[i][j][2] = 0.f; acc[i][j][3] = 0.f; }

  const int nkt = K >> 5;
  for (int kt = 0; kt < nkt; ++kt) {
    const int kb = kt * 32;
    __syncthreads();  // prior tile's LDS reads done
#pragma unroll
    for (int i = 0; i < 4; ++i) {
      const int c = wave * 4 + i;  // 0..15 : 0-7 = A chunks, 8-15 = B chunks
      if (c < 8) {
        gload_lds16(A + (size_t)(m0 + c * 16 + lh) * K + kb + q8, &As[c * 512 + lane * 8]);
      } else {
        const int rb = c - 8;
        gload_lds16(Bw + (size_t)(n0 + rb * 16 + lh) * K + kb + q8, &Bs[rb * 512 + lane * 8]);
      }
    }
    __syncthreads();  // drains DMA, staged tile visible
    s16x8 af[4], bf4[4];
#pragma unroll
    for (int mb = 0; mb < 4; ++mb)
      af[mb] = *reinterpret_cast<const s16x8*>(&As[(wm * 4 + mb) * 512 + lane * 8]);
#pragma unroll
    for (int nb = 0; nb < 4; ++nb)
      bf4[nb] = *reinterpret_cast<const s16x8*>(&Bs[(wn * 4 + nb) * 512 + lane * 8]);
#pragma unroll
    for (int mb = 0; mb < 4; ++mb)
#pragma unroll
      for (int nb = 0; nb < 4; ++nb)
        acc[mb][nb] = __builtin_amdgcn_mfma_f32_16x16x32_bf16(af[mb], bf4[nb], acc[mb][nb], 0, 0, 0);
  }
#pragma unroll
  for (int mb = 0; mb < 4; ++mb)
#pragma unroll
    for (int nb = 0; nb < 4; ++nb) {
      const int col = n0 + wn * 64 + nb * 16 + lh;
#pragma unroll
      for (int r = 0; r < 4; ++r) {
        const int row = m0 + wm * 64 + mb * 16 + quad * 4 + r;
        store_out(&C[(size_t)row * N + col], acc[mb][nb][r]);
      }
    }
}

// ---------------- RoPE + pre-scale: raw QKV -> Qs(q/8), Q2s(0.0125 q^2), K, K^2 ----------------
__global__ __launch_bounds__(256) void rope_kernel(const u16* __restrict__ raw,
                                                   u16* __restrict__ Qs, u16* __restrict__ Q2s,
                                                   u16* __restrict__ Kb, u16* __restrict__ K2b) {
  int idx = blockIdx.x * 256 + threadIdx.x;  // 0 .. 4194303
  int which = idx >> 21;                     // 0 = Q, 1 = K
  int id = idx & 0x1FFFFF;
  int d = id & 31;
  int s = (id >> 5) & 2047;
  int bh = id >> 16;                         // b*16 + h
  int b = bh >> 4;
  int h = bh & 15;
  const u16* r = raw + (size_t)(b * 2048 + s) * 3072 + which * 1024 + h * 64 + d;
  float v1 = bf2f(r[0]);
  float v2 = bf2f(r[32]);
  float invf = __expf((float)d * -0.2878231366f);  // 10000^(-d/32)
  float ang = (float)s * invf;
  float sv, cv;
  __sincosf(ang, &sv, &cv);
  float e0 = v1 * cv - v2 * sv;
  float e1 = v2 * cv + v1 * sv;
  size_t ofs = (size_t)(bh * 2048 + s) * 64 + d;
  if (which == 0) {
    Qs[ofs]       = f2bf(e0 * 0.125f);
    Qs[ofs + 32]  = f2bf(e1 * 0.125f);
    Q2s[ofs]      = f2bf(e0 * e0 * 0.0125f);
    Q2s[ofs + 32] = f2bf(e1 * e1 * 0.0125f);
  } else {
    Kb[ofs]       = f2bf(e0);
    Kb[ofs + 32]  = f2bf(e1);
    K2b[ofs]      = f2bf(e0 * e0);
    K2b[ofs + 32] = f2bf(e1 * e1);
  }
}

// ---------------- V transpose: raw V cols -> Vt (B,H,64,S) bf16 ----------------
__global__ __launch_bounds__(256) void transpose_v(const u16* __restrict__ raw,
                                                   u16* __restrict__ Vt) {
  int st = blockIdx.x, bh = blockIdx.y;
  int b = bh >> 4, h = bh & 15;
  __shared__ u16 tile[64 * 72];
  int tid = threadIdx.x;
#pragma unroll
  for (int it = 0; it < 4; ++it) {
    int c = it * 256 + tid;
    int sr = c >> 4, d4 = c & 15;
    u16x4 v = *reinterpret_cast<const u16x4*>(
        raw + (size_t)(b * 2048 + st * 64 + sr) * 3072 + 2048 + h * 64 + d4 * 4);
    *reinterpret_cast<u16x4*>(&tile[sr * 72 + d4 * 4]) = v;
  }
  __syncthreads();
#pragma unroll
  for (int it = 0; it < 4; ++it) {
    int c = it * 256 + tid;
    int dd = c >> 4, s4 = c & 15;
    u16x4 v;
#pragma unroll
    for (int j = 0; j < 4; ++j) v[j] = tile[(s4 * 4 + j) * 72 + dd];
    *reinterpret_cast<u16x4*>(Vt + (size_t)(bh * 64 + dd) * 2048 + st * 64 + s4 * 4) = v;
  }
}

// ---------------- barrier-free causal amplified attention, fixed-max + split-K ----------------
// Q-tile 128 rows/block (4 waves x 32 rows). K/K2/V fragments read DIRECTLY from
// global (B-layout, L1-shared across the 4 waves); only wave-private Pbuf in LDS
// => ZERO __syncthreads in the kernel, waves free-run.
// Fixed softmax max 8 => partials over disjoint key ranges are directly addable.
// grid (28, 32): bx<16: qi=15-(bx>>1) halves -> Opart; bx 16..23: qi=7-((bx-16)>>1)
// halves -> Opart2; bx 24..27: qi=27-bx whole, inline epilogue.
__global__ __launch_bounds__(256, 4) void attn_kernel(const u16* __restrict__ Qs,
                                                      const u16* __restrict__ Q2s,
                                                      const u16* __restrict__ Kb,
                                                      const u16* __restrict__ K2b,
                                                      const u16* __restrict__ Vt,
                                                      const float* __restrict__ gate,
                                                      u16* __restrict__ attn,
                                                      float* __restrict__ Opart,
                                                      float* __restrict__ Lpart,
                                                      float* __restrict__ Opart2,
                                                      float* __restrict__ Lpart2) {
  const int bx = blockIdx.x;
  int qi, kt0, kt1, half, which;
  bool split;
  if (bx < 16) {
    qi = 15 - (bx >> 1); half = bx & 1; split = true; which = 0;
    const int nk = qi + 1; kt0 = half * nk; kt1 = kt0 + nk - 1;
  } else if (bx < 24) {
    const int t = bx - 16;
    qi = 7 - (t >> 1); half = t & 1; split = true; which = 1;
    const int nk = qi + 1; kt0 = half * nk; kt1 = kt0 + nk - 1;
  } else {
    qi = 27 - bx; split = false; which = 0; half = 0; kt0 = 0; kt1 = 2 * qi + 1;
  }
  const int bh = blockIdx.y;
  const int tid = threadIdx.x, lane = tid & 63, wave = tid >> 6;
  const int lh = lane & 15, quad = lane >> 4;
  const int b = bh >> 4, h = bh & 15;
  __shared__ u16 Pbuf[4][2][1152];  // per (wave, mb): 16 rows x 72
  const int base = qi * 128 + wave * 32;   // wave's first Q row
  const int q8 = quad * 8;

  // Q fragments (A-layout): m = lh, k = kk*32 + quad*8 + j ; pre-scaled in memory
  s16x8 qf[2][2], q2f[2][2];
#pragma unroll
  for (int mb = 0; mb < 2; ++mb) {
    const size_t qoff = (size_t)(bh * 2048 + base + mb * 16 + lh) * 64 + q8;
#pragma unroll
    for (int kk = 0; kk < 2; ++kk) {
      qf[mb][kk]  = *reinterpret_cast<const s16x8*>(Qs + qoff + kk * 32);
      q2f[mb][kk] = *reinterpret_cast<const s16x8*>(Q2s + qoff + kk * 32);
    }
  }

  // fragment base pointers (B-layout: n = lh, k = kk*32 + quad*8 + j)
  const u16* kfp  = Kb  + (size_t)(bh * 2048 + lh) * 64 + q8;   // + kt*4096 + nb*1024 + kk*32
  const u16* k2fp = K2b + (size_t)(bh * 2048 + lh) * 64 + q8;
  const u16* vfp  = Vt  + (size_t)(bh * 64 + lh) * 2048 + q8;   // + nb*32768 + kt*64 + kk*32

  f32x4 oacc[2][4];
  float lsum[2][4];
#pragma unroll
  for (int mb = 0; mb < 2; ++mb)
#pragma unroll
    for (int nb = 0; nb < 4; ++nb) { oacc[mb][nb][0] = 0.f; oacc[mb][nb][1] = 0.f; oacc[mb][nb][2] = 0.f; oacc[mb][nb][3] = 0.f; }
#pragma unroll
  for (int mb = 0; mb < 2; ++mb)
#pragma unroll
    for (int r = 0; r < 4; ++r) lsum[mb][r] = 0.f;
  float gw[4];
#pragma unroll
  for (int nb = 0; nb < 4; ++nb) gw[nb] = gate[nb * 16 + lh];

  const int wmaxrow = base + 31;
  for (int kt = kt0; kt <= kt1; ++kt) {
    if (kt * 64 > wmaxrow) continue;  // fully masked tile (only possible at range end)

    f32x4 sacc[2][4];
#pragma unroll
    for (int mb = 0; mb < 2; ++mb)
#pragma unroll
      for (int nb = 0; nb < 4; ++nb) { sacc[mb][nb][0] = -8.f; sacc[mb][nb][1] = -8.f; sacc[mb][nb][2] = -8.f; sacc[mb][nb][3] = -8.f; }
#pragma unroll
    for (int nb = 0; nb < 4; ++nb)
#pragma unroll
      for (int kk = 0; kk < 2; ++kk) {
        s16x8 kf  = *reinterpret_cast<const s16x8*>(kfp  + kt * 4096 + nb * 1024 + kk * 32);
        s16x8 k2f = *reinterpret_cast<const s16x8*>(k2fp + kt * 4096 + nb * 1024 + kk * 32);
#pragma unroll
        for (int mb = 0; mb < 2; ++mb) {
          sacc[mb][nb] = __builtin_amdgcn_mfma_f32_16x16x32_bf16(qf[mb][kk],  kf,  sacc[mb][nb], 0, 0, 0);
          sacc[mb][nb] = __builtin_amdgcn_mfma_f32_16x16x32_bf16(q2f[mb][kk], k2f, sacc[mb][nb], 0, 0, 0);
        }
      }
    // V fragments (global; latency hides under exp/pack)
    s16x8 vf[2][4];
#pragma unroll
    for (int kk = 0; kk < 2; ++kk)
#pragma unroll
      for (int nb = 0; nb < 4; ++nb)
        vf[kk][nb] = *reinterpret_cast<const s16x8*>(vfp + (size_t)nb * 32768 + kt * 64 + kk * 32);

    if (kt * 64 + 63 > base) {  // tiles overlapping the diagonal: elementwise mask
#pragma unroll
      for (int mb = 0; mb < 2; ++mb)
#pragma unroll
        for (int nb = 0; nb < 4; ++nb) {
          const int colg = kt * 64 + nb * 16 + lh;
#pragma unroll
          for (int r = 0; r < 4; ++r) {
            const int rowg = base + mb * 16 + quad * 4 + r;
            if (colg > rowg) sacc[mb][nb][r] = -1e9f;
          }
        }
    }
    // p = exp(s - 8); per-lane row-sum partials (reduced once after the loop)
#pragma unroll
    for (int mb = 0; mb < 2; ++mb)
#pragma unroll
      for (int nb = 0; nb < 4; ++nb)
#pragma unroll
        for (int r = 0; r < 4; ++r) {
          float pv = __expf(sacc[mb][nb][r]);
          lsum[mb][r] += pv;
          Pbuf[wave][mb][(quad * 4 + r) * 72 + nb * 16 + lh] = f2bf(pv);
        }
    // PV: P through LDS (C-layout -> A-layout), wave-private, no barrier
#pragma unroll
    for (int mb = 0; mb < 2; ++mb)
#pragma unroll
      for (int kk = 0; kk < 2; ++kk) {
        s16x8 pf = *reinterpret_cast<const s16x8*>(&Pbuf[wave][mb][lh * 72 + kk * 32 + q8]);
#pragma unroll
        for (int nb = 0; nb < 4; ++nb)
          oacc[mb][nb] = __builtin_amdgcn_mfma_f32_16x16x32_bf16(pf, vf[kk][nb], oacc[mb][nb], 0, 0, 0);
      }
  }
  // reduce row sums across the 16 lanes holding each row
#pragma unroll
  for (int mb = 0; mb < 2; ++mb)
#pragma unroll
    for (int r = 0; r < 4; ++r) {
      float rs = lsum[mb][r];
#pragma unroll
      for (int off = 1; off < 16; off <<= 1) rs += __shfl_xor(rs, off);
      lsum[mb][r] = rs;
    }
  if (split) {
    // unnormalized partials to ws (fp32)
#pragma unroll
    for (int mb = 0; mb < 2; ++mb)
#pragma unroll
      for (int r = 0; r < 4; ++r) {
        const int rowg = base + mb * 16 + quad * 4 + r;
        if (which == 0) {
          const size_t orow = (size_t)half * 32768 + bh * 1024 + (rowg - 1024);
          if (lh == 0) Lpart[orow] = lsum[mb][r];
#pragma unroll
          for (int nb = 0; nb < 4; ++nb)
            Opart[orow * 64 + nb * 16 + lh] = oacc[mb][nb][r];
        } else {
          const size_t orow = (size_t)half * 16384 + bh * 512 + (rowg - 512);
          if (lh == 0) Lpart2[orow] = lsum[mb][r];
#pragma unroll
          for (int nb = 0; nb < 4; ++nb)
            Opart2[orow * 64 + nb * 16 + lh] = oacc[mb][nb][r];
        }
      }
  } else {
    // finalize: o/l, epilogue o + 0.05*o^2*g[d] (out2==out1 identity)
#pragma unroll
    for (int mb = 0; mb < 2; ++mb)
#pragma unroll
      for (int r = 0; r < 4; ++r) {
        const float invl = 1.0f / lsum[mb][r];
        const int rows = base + mb * 16 + quad * 4 + r;
#pragma unroll
        for (int nb = 0; nb < 4; ++nb) {
          float o = oacc[mb][nb][r] * invl;
          float val = o + 0.05f * o * o * gw[nb];
          attn[(size_t)(b * 2048 + rows) * 1024 + h * 64 + nb * 16 + lh] = f2bf(val);
        }
      }
  }
}

// ---------------- combine split-K partials (rows 512..2047) ----------------
__global__ __launch_bounds__(256) void combine_kernel(const float* __restrict__ Opart,
                                                      const float* __restrict__ Lpart,
                                                      const float* __restrict__ Opart2,
                                                      const float* __restrict__ Lpart2,
                                                      const float* __restrict__ gate,
                                                      u16* __restrict__ attn) {
  int idx = blockIdx.x * 256 + threadIdx.x;   // 0 .. 3145727
  int d = idx & 63;
  int r_all = idx >> 6;
  float o, l;
  int bh, s;
  if (r_all < 32768) {            // rows s >= 1024 (qi >= 8)
    o = Opart[idx] + Opart[idx + 2097152];
    l = Lpart[r_all] + Lpart[r_all + 32768];
    bh = r_all >> 10; s = 1024 + (r_all & 1023);
  } else {                        // rows 512..1023 (qi 4..7)
    const int r2 = r_all - 32768;
    const int i2 = idx - 2097152;
    o = Opart2[i2] + Opart2[i2 + 1048576];
    l = Lpart2[r2] + Lpart2[r2 + 16384];
    bh = r2 >> 9; s = 512 + (r2 & 511);
  }
  o /= l;
  float val = o + 0.05f * o * o * gate[d];
  int b = bh >> 4, h = bh & 15;
  attn[(size_t)(b * 2048 + s) * 1024 + h * 64 + d] = f2bf(val);
}

extern "C" void kernel_launch(void* const* d_in, const int* in_sizes, int n_in,
                              void* d_out, int out_size, void* d_ws, size_t ws_size,
                              hipStream_t stream) {
  (void)in_sizes; (void)n_in; (void)out_size; (void)ws_size;
  const float* x    = (const float*)d_in[0];
  const float* Wq   = (const float*)d_in[1];
  const float* Wk   = (const float*)d_in[2];
  const float* Wv   = (const float*)d_in[3];
  const float* Wo   = (const float*)d_in[4];
  const float* gate = (const float*)d_in[5];

  u16* ws    = (u16*)d_ws;
  u16* xbf   = ws;                    // 4096x1024 (dead after QKV gemm)
  u16* wbf   = xbf + 4194304;         // 3072x1024 (Wq|Wk|Wv rows)
  u16* wobf  = wbf + 3145728;         // 1024x1024
  u16* raw   = wobf + 1048576;        // 4096x3072 QKV gemm out (dead after rope+transpose)
  u16* Qsb   = raw + 12582912;        // (B,H,S,64) q/8
  u16* Kbb   = Qsb + 4194304;         // (B,H,S,64)
  u16* K2bb  = Kbb + 4194304;         // (B,H,S,64)
  u16* Vtb   = K2bb + 4194304;        // (B,H,64,S)
  float* Opart = (float*)(Vtb + 4194304);  // 2 x 32 x 1024 x 64 fp32 (16.8 MB)
  float* Lpart = Opart + 4194304;          // 2 x 32 x 1024 fp32
  u16* Q2sb  = xbf;                   // alias: written by rope (after gemm)
  u16* attnb = raw;                   // alias: attn out (first 4.19M u16 of raw)
  float* Opart2 = (float*)(raw + 4194304); // alias: raw tail, 2 x 32 x 512 x 64 fp32 (8.4 MB)
  float* Lpart2 = Opart2 + 2097152;        // 2 x 32 x 512 fp32

  cvt_kernel<<<4096, 256, 0, stream>>>(x, xbf, 1048576);
  cvt_w<<<4096, 256, 0, stream>>>(Wq, Wk, Wv, Wo, wbf, wobf);

  gemm_bt<u16><<<dim3(24, 32), 256, 0, stream>>>(xbf, wbf, raw, 3072, 1024);
  rope_kernel<<<16384, 256, 0, stream>>>(raw, Qsb, Q2sb, Kbb, K2bb);
  transpose_v<<<dim3(32, 32), 256, 0, stream>>>(raw, Vtb);
  attn_kernel<<<dim3(28, 32), 256, 0, stream>>>(Qsb, Q2sb, Kbb, K2bb, Vtb, gate, attnb,
                                                Opart, Lpart, Opart2, Lpart2);
  combine_kernel<<<12288, 256, 0, stream>>>(Opart, Lpart, Opart2, Lpart2, gate, attnb);
  gemm_bt<float><<<dim3(8, 32), 256, 0, stream>>>(attnb, wobf, (float*)d_out, 1024, 1024);
}

// Round 8
// 337.897 us; speedup vs baseline: 1.1807x; 1.1807x over previous
//
#include <hip/hip_runtime.h>

typedef unsigned short u16;
typedef __attribute__((ext_vector_type(4))) unsigned short u16x4;
typedef __attribute__((ext_vector_type(8))) unsigned short u16x8;
typedef __attribute__((ext_vector_type(8))) short s16x8;
typedef __attribute__((ext_vector_type(4))) float f32x4;

__device__ __forceinline__ u16 f2bf(float f) {
  unsigned int u = __float_as_uint(f);
  u += 0x7FFFu + ((u >> 16) & 1u);   // RNE
  return (u16)(u >> 16);
}
__device__ __forceinline__ float bf2f(u16 h) {
  return __uint_as_float(((unsigned int)h) << 16);
}

// async global->LDS, 16B per lane; base = lane0's lds ptr, lane i writes base+i*16B.
__device__ __forceinline__ void gload_lds16(const u16* g, u16* l) {
  __builtin_amdgcn_global_load_lds(
      (const __attribute__((address_space(1))) unsigned int*)(g),
      (__attribute__((address_space(3))) unsigned int*)(l), 16, 0, 0);
}

// ---------------- fp32 -> bf16 convert (x4 vectorized) ----------------
__global__ __launch_bounds__(256) void cvt_kernel(const float* __restrict__ src,
                                                  u16* __restrict__ dst, int n4) {
  int i = blockIdx.x * 256 + threadIdx.x;
  if (i >= n4) return;
  float4 v = reinterpret_cast<const float4*>(src)[i];
  u16x4 o;
  o.x = f2bf(v.x); o.y = f2bf(v.y); o.z = f2bf(v.z); o.w = f2bf(v.w);
  reinterpret_cast<u16x4*>(dst)[i] = o;
}

// all four 1024x1024 weights in one launch
__global__ __launch_bounds__(256) void cvt_w(const float* __restrict__ Wq,
                                             const float* __restrict__ Wk,
                                             const float* __restrict__ Wv,
                                             const float* __restrict__ Wo,
                                             u16* __restrict__ wbf, u16* __restrict__ wobf) {
  int blk = blockIdx.x;           // 0..4095
  int sel = blk >> 10;
  const float* src = (sel == 0) ? Wq : (sel == 1) ? Wk : (sel == 2) ? Wv : Wo;
  u16* dst = (sel < 3) ? (wbf + (size_t)sel * 1048576) : wobf;
  int i = (blk & 1023) * 256 + threadIdx.x;
  float4 v = reinterpret_cast<const float4*>(src)[i];
  u16x4 o;
  o.x = f2bf(v.x); o.y = f2bf(v.y); o.z = f2bf(v.z); o.w = f2bf(v.w);
  reinterpret_cast<u16x4*>(dst)[i] = o;
}

// ---------------- GEMM: C[m][n] = sum_k A[m][k] * B[n][k] (B^T input) ----------------
// 128x128 tile, BK=32, global_load_lds staging, chunk = 16 rows x 32 cols = 512 u16.
__device__ __forceinline__ void store_out(float* p, float v) { *p = v; }
__device__ __forceinline__ void store_out(u16* p, float v) { *p = f2bf(v); }

template <typename OutT>
__global__ __launch_bounds__(256) void gemm_bt(const u16* __restrict__ A,
                                               const u16* __restrict__ Bw,
                                               OutT* __restrict__ C, int N, int K) {
  __shared__ u16 As[4096];
  __shared__ u16 Bs[4096];
  const int tid = threadIdx.x;
  const int lane = tid & 63;
  const int wave = tid >> 6;
  const int wm = wave >> 1, wn = wave & 1;
  const int lh = lane & 15, quad = lane >> 4;
  const int q8 = quad * 8;
  const int m0 = blockIdx.y * 128, n0 = blockIdx.x * 128;

  f32x4 acc[4][4];
#pragma unroll
  for (int i = 0; i < 4; ++i)
#pragma unroll
    for (int j = 0; j < 4; ++j) { acc[i][j][0] = 0.f; acc[i][j][1] = 0.f; acc[i][j][2] = 0.f; acc[i][j][3] = 0.f; }

  const int nkt = K >> 5;
  for (int kt = 0; kt < nkt; ++kt) {
    const int kb = kt * 32;
    __syncthreads();  // prior tile's LDS reads done
#pragma unroll
    for (int i = 0; i < 4; ++i) {
      const int c = wave * 4 + i;  // 0..15 : 0-7 = A chunks, 8-15 = B chunks
      if (c < 8) {
        gload_lds16(A + (size_t)(m0 + c * 16 + lh) * K + kb + q8, &As[c * 512 + lane * 8]);
      } else {
        const int rb = c - 8;
        gload_lds16(Bw + (size_t)(n0 + rb * 16 + lh) * K + kb + q8, &Bs[rb * 512 + lane * 8]);
      }
    }
    __syncthreads();  // drains DMA, staged tile visible
    s16x8 af[4], bf4[4];
#pragma unroll
    for (int mb = 0; mb < 4; ++mb)
      af[mb] = *reinterpret_cast<const s16x8*>(&As[(wm * 4 + mb) * 512 + lane * 8]);
#pragma unroll
    for (int nb = 0; nb < 4; ++nb)
      bf4[nb] = *reinterpret_cast<const s16x8*>(&Bs[(wn * 4 + nb) * 512 + lane * 8]);
#pragma unroll
    for (int mb = 0; mb < 4; ++mb)
#pragma unroll
      for (int nb = 0; nb < 4; ++nb)
        acc[mb][nb] = __builtin_amdgcn_mfma_f32_16x16x32_bf16(af[mb], bf4[nb], acc[mb][nb], 0, 0, 0);
  }
#pragma unroll
  for (int mb = 0; mb < 4; ++mb)
#pragma unroll
    for (int nb = 0; nb < 4; ++nb) {
      const int col = n0 + wn * 64 + nb * 16 + lh;
#pragma unroll
      for (int r = 0; r < 4; ++r) {
        const int row = m0 + wm * 64 + mb * 16 + quad * 4 + r;
        store_out(&C[(size_t)row * N + col], acc[mb][nb][r]);
      }
    }
}

// ---------------- RoPE + pre-scale: raw QKV -> Qs(q/8), Q2s(0.0125 q^2), K, K^2 ----------------
__global__ __launch_bounds__(256) void rope_kernel(const u16* __restrict__ raw,
                                                   u16* __restrict__ Qs, u16* __restrict__ Q2s,
                                                   u16* __restrict__ Kb, u16* __restrict__ K2b) {
  int idx = blockIdx.x * 256 + threadIdx.x;  // 0 .. 4194303
  int which = idx >> 21;                     // 0 = Q, 1 = K
  int id = idx & 0x1FFFFF;
  int d = id & 31;
  int s = (id >> 5) & 2047;
  int bh = id >> 16;                         // b*16 + h
  int b = bh >> 4;
  int h = bh & 15;
  const u16* r = raw + (size_t)(b * 2048 + s) * 3072 + which * 1024 + h * 64 + d;
  float v1 = bf2f(r[0]);
  float v2 = bf2f(r[32]);
  float invf = __expf((float)d * -0.2878231366f);  // 10000^(-d/32)
  float ang = (float)s * invf;
  float sv, cv;
  __sincosf(ang, &sv, &cv);
  float e0 = v1 * cv - v2 * sv;
  float e1 = v2 * cv + v1 * sv;
  size_t ofs = (size_t)(bh * 2048 + s) * 64 + d;
  if (which == 0) {
    Qs[ofs]       = f2bf(e0 * 0.125f);
    Qs[ofs + 32]  = f2bf(e1 * 0.125f);
    Q2s[ofs]      = f2bf(e0 * e0 * 0.0125f);
    Q2s[ofs + 32] = f2bf(e1 * e1 * 0.0125f);
  } else {
    Kb[ofs]       = f2bf(e0);
    Kb[ofs + 32]  = f2bf(e1);
    K2b[ofs]      = f2bf(e0 * e0);
    K2b[ofs + 32] = f2bf(e1 * e1);
  }
}

// ---------------- V transpose: raw V cols -> Vt (B,H,64,S) bf16 ----------------
__global__ __launch_bounds__(256) void transpose_v(const u16* __restrict__ raw,
                                                   u16* __restrict__ Vt) {
  int st = blockIdx.x, bh = blockIdx.y;
  int b = bh >> 4, h = bh & 15;
  __shared__ u16 tile[64 * 72];
  int tid = threadIdx.x;
#pragma unroll
  for (int it = 0; it < 4; ++it) {
    int c = it * 256 + tid;
    int sr = c >> 4, d4 = c & 15;
    u16x4 v = *reinterpret_cast<const u16x4*>(
        raw + (size_t)(b * 2048 + st * 64 + sr) * 3072 + 2048 + h * 64 + d4 * 4);
    *reinterpret_cast<u16x4*>(&tile[sr * 72 + d4 * 4]) = v;
  }
  __syncthreads();
#pragma unroll
  for (int it = 0; it < 4; ++it) {
    int c = it * 256 + tid;
    int dd = c >> 4, s4 = c & 15;
    u16x4 v;
#pragma unroll
    for (int j = 0; j < 4; ++j) v[j] = tile[(s4 * 4 + j) * 72 + dd];
    *reinterpret_cast<u16x4*>(Vt + (size_t)(bh * 64 + dd) * 2048 + st * 64 + s4 * 4) = v;
  }
}

// ---------------- barrier-free causal amplified attention, fixed-max + split-K ----------------
// Q-tile 128 rows/block (4 waves x 32 rows). K/K2/V fragments read DIRECTLY from
// global (B-layout, L1-shared across the 4 waves); only wave-private Pbuf in LDS
// => ZERO __syncthreads in the kernel, waves free-run.
// __launch_bounds__(256, 2): allocator gets ~128 VGPRs -- (256,4) in r7 capped at
// 64 VGPRs and spilled to scratch (231 MB HBM writes, 2.4x regression).
// Fixed softmax max 8 => partials over disjoint key ranges are directly addable.
// grid (28, 32): bx<16: qi=15-(bx>>1) halves -> Opart; bx 16..23: qi=7-((bx-16)>>1)
// halves -> Opart2; bx 24..27: qi=27-bx whole, inline epilogue.
__global__ __launch_bounds__(256, 2) void attn_kernel(const u16* __restrict__ Qs,
                                                      const u16* __restrict__ Q2s,
                                                      const u16* __restrict__ Kb,
                                                      const u16* __restrict__ K2b,
                                                      const u16* __restrict__ Vt,
                                                      const float* __restrict__ gate,
                                                      u16* __restrict__ attn,
                                                      float* __restrict__ Opart,
                                                      float* __restrict__ Lpart,
                                                      float* __restrict__ Opart2,
                                                      float* __restrict__ Lpart2) {
  const int bx = blockIdx.x;
  int qi, kt0, kt1, half, which;
  bool split;
  if (bx < 16) {
    qi = 15 - (bx >> 1); half = bx & 1; split = true; which = 0;
    const int nk = qi + 1; kt0 = half * nk; kt1 = kt0 + nk - 1;
  } else if (bx < 24) {
    const int t = bx - 16;
    qi = 7 - (t >> 1); half = t & 1; split = true; which = 1;
    const int nk = qi + 1; kt0 = half * nk; kt1 = kt0 + nk - 1;
  } else {
    qi = 27 - bx; split = false; which = 0; half = 0; kt0 = 0; kt1 = 2 * qi + 1;
  }
  const int bh = blockIdx.y;
  const int tid = threadIdx.x, lane = tid & 63, wave = tid >> 6;
  const int lh = lane & 15, quad = lane >> 4;
  const int b = bh >> 4, h = bh & 15;
  __shared__ u16 Pbuf[4][2][1152];  // per (wave, mb): 16 rows x 72
  const int base = qi * 128 + wave * 32;   // wave's first Q row
  const int q8 = quad * 8;

  // Q fragments (A-layout): m = lh, k = kk*32 + quad*8 + j ; pre-scaled in memory
  s16x8 qf[2][2], q2f[2][2];
#pragma unroll
  for (int mb = 0; mb < 2; ++mb) {
    const size_t qoff = (size_t)(bh * 2048 + base + mb * 16 + lh) * 64 + q8;
#pragma unroll
    for (int kk = 0; kk < 2; ++kk) {
      qf[mb][kk]  = *reinterpret_cast<const s16x8*>(Qs + qoff + kk * 32);
      q2f[mb][kk] = *reinterpret_cast<const s16x8*>(Q2s + qoff + kk * 32);
    }
  }

  // fragment base pointers (B-layout: n = lh, k = kk*32 + quad*8 + j)
  const u16* kfp  = Kb  + (size_t)(bh * 2048 + lh) * 64 + q8;   // + kt*4096 + nb*1024 + kk*32
  const u16* k2fp = K2b + (size_t)(bh * 2048 + lh) * 64 + q8;
  const u16* vfp  = Vt  + (size_t)(bh * 64 + lh) * 2048 + q8;   // + nb*32768 + kt*64 + kk*32

  f32x4 oacc[2][4];
  float lsum[2][4];
#pragma unroll
  for (int mb = 0; mb < 2; ++mb)
#pragma unroll
    for (int nb = 0; nb < 4; ++nb) { oacc[mb][nb][0] = 0.f; oacc[mb][nb][1] = 0.f; oacc[mb][nb][2] = 0.f; oacc[mb][nb][3] = 0.f; }
#pragma unroll
  for (int mb = 0; mb < 2; ++mb)
#pragma unroll
    for (int r = 0; r < 4; ++r) lsum[mb][r] = 0.f;
  float gw[4];
#pragma unroll
  for (int nb = 0; nb < 4; ++nb) gw[nb] = gate[nb * 16 + lh];

  const int wmaxrow = base + 31;
  for (int kt = kt0; kt <= kt1; ++kt) {
    if (kt * 64 > wmaxrow) continue;  // fully masked tile (only possible at range end)

    f32x4 sacc[2][4];
#pragma unroll
    for (int mb = 0; mb < 2; ++mb)
#pragma unroll
      for (int nb = 0; nb < 4; ++nb) { sacc[mb][nb][0] = -8.f; sacc[mb][nb][1] = -8.f; sacc[mb][nb][2] = -8.f; sacc[mb][nb][3] = -8.f; }
#pragma unroll
    for (int nb = 0; nb < 4; ++nb)
#pragma unroll
      for (int kk = 0; kk < 2; ++kk) {
        s16x8 kf  = *reinterpret_cast<const s16x8*>(kfp  + kt * 4096 + nb * 1024 + kk * 32);
        s16x8 k2f = *reinterpret_cast<const s16x8*>(k2fp + kt * 4096 + nb * 1024 + kk * 32);
#pragma unroll
        for (int mb = 0; mb < 2; ++mb) {
          sacc[mb][nb] = __builtin_amdgcn_mfma_f32_16x16x32_bf16(qf[mb][kk],  kf,  sacc[mb][nb], 0, 0, 0);
          sacc[mb][nb] = __builtin_amdgcn_mfma_f32_16x16x32_bf16(q2f[mb][kk], k2f, sacc[mb][nb], 0, 0, 0);
        }
      }
    // V fragments (global; latency hides under exp/pack)
    s16x8 vf[2][4];
#pragma unroll
    for (int kk = 0; kk < 2; ++kk)
#pragma unroll
      for (int nb = 0; nb < 4; ++nb)
        vf[kk][nb] = *reinterpret_cast<const s16x8*>(vfp + (size_t)nb * 32768 + kt * 64 + kk * 32);

    if (kt * 64 + 63 > base) {  // tiles overlapping the diagonal: elementwise mask
#pragma unroll
      for (int mb = 0; mb < 2; ++mb)
#pragma unroll
        for (int nb = 0; nb < 4; ++nb) {
          const int colg = kt * 64 + nb * 16 + lh;
#pragma unroll
          for (int r = 0; r < 4; ++r) {
            const int rowg = base + mb * 16 + quad * 4 + r;
            if (colg > rowg) sacc[mb][nb][r] = -1e9f;
          }
        }
    }
    // p = exp(s - 8); per-lane row-sum partials (reduced once after the loop)
#pragma unroll
    for (int mb = 0; mb < 2; ++mb)
#pragma unroll
      for (int nb = 0; nb < 4; ++nb)
#pragma unroll
        for (int r = 0; r < 4; ++r) {
          float pv = __expf(sacc[mb][nb][r]);
          lsum[mb][r] += pv;
          Pbuf[wave][mb][(quad * 4 + r) * 72 + nb * 16 + lh] = f2bf(pv);
        }
    // PV: P through LDS (C-layout -> A-layout), wave-private, no barrier
#pragma unroll
    for (int mb = 0; mb < 2; ++mb)
#pragma unroll
      for (int kk = 0; kk < 2; ++kk) {
        s16x8 pf = *reinterpret_cast<const s16x8*>(&Pbuf[wave][mb][lh * 72 + kk * 32 + q8]);
#pragma unroll
        for (int nb = 0; nb < 4; ++nb)
          oacc[mb][nb] = __builtin_amdgcn_mfma_f32_16x16x32_bf16(pf, vf[kk][nb], oacc[mb][nb], 0, 0, 0);
      }
  }
  // reduce row sums across the 16 lanes holding each row
#pragma unroll
  for (int mb = 0; mb < 2; ++mb)
#pragma unroll
    for (int r = 0; r < 4; ++r) {
      float rs = lsum[mb][r];
#pragma unroll
      for (int off = 1; off < 16; off <<= 1) rs += __shfl_xor(rs, off);
      lsum[mb][r] = rs;
    }
  if (split) {
    // unnormalized partials to ws (fp32)
#pragma unroll
    for (int mb = 0; mb < 2; ++mb)
#pragma unroll
      for (int r = 0; r < 4; ++r) {
        const int rowg = base + mb * 16 + quad * 4 + r;
        if (which == 0) {
          const size_t orow = (size_t)half * 32768 + bh * 1024 + (rowg - 1024);
          if (lh == 0) Lpart[orow] = lsum[mb][r];
#pragma unroll
          for (int nb = 0; nb < 4; ++nb)
            Opart[orow * 64 + nb * 16 + lh] = oacc[mb][nb][r];
        } else {
          const size_t orow = (size_t)half * 16384 + bh * 512 + (rowg - 512);
          if (lh == 0) Lpart2[orow] = lsum[mb][r];
#pragma unroll
          for (int nb = 0; nb < 4; ++nb)
            Opart2[orow * 64 + nb * 16 + lh] = oacc[mb][nb][r];
        }
      }
  } else {
    // finalize: o/l, epilogue o + 0.05*o^2*g[d] (out2==out1 identity)
#pragma unroll
    for (int mb = 0; mb < 2; ++mb)
#pragma unroll
      for (int r = 0; r < 4; ++r) {
        const float invl = 1.0f / lsum[mb][r];
        const int rows = base + mb * 16 + quad * 4 + r;
#pragma unroll
        for (int nb = 0; nb < 4; ++nb) {
          float o = oacc[mb][nb][r] * invl;
          float val = o + 0.05f * o * o * gw[nb];
          attn[(size_t)(b * 2048 + rows) * 1024 + h * 64 + nb * 16 + lh] = f2bf(val);
        }
      }
  }
}

// ---------------- combine split-K partials (rows 512..2047) ----------------
__global__ __launch_bounds__(256) void combine_kernel(const float* __restrict__ Opart,
                                                      const float* __restrict__ Lpart,
                                                      const float* __restrict__ Opart2,
                                                      const float* __restrict__ Lpart2,
                                                      const float* __restrict__ gate,
                                                      u16* __restrict__ attn) {
  int idx = blockIdx.x * 256 + threadIdx.x;   // 0 .. 3145727
  int d = idx & 63;
  int r_all = idx >> 6;
  float o, l;
  int bh, s;
  if (r_all < 32768) {            // rows s >= 1024 (qi >= 8)
    o = Opart[idx] + Opart[idx + 2097152];
    l = Lpart[r_all] + Lpart[r_all + 32768];
    bh = r_all >> 10; s = 1024 + (r_all & 1023);
  } else {                        // rows 512..1023 (qi 4..7)
    const int r2 = r_all - 32768;
    const int i2 = idx - 2097152;
    o = Opart2[i2] + Opart2[i2 + 1048576];
    l = Lpart2[r2] + Lpart2[r2 + 16384];
    bh = r2 >> 9; s = 512 + (r2 & 511);
  }
  o /= l;
  float val = o + 0.05f * o * o * gate[d];
  int b = bh >> 4, h = bh & 15;
  attn[(size_t)(b * 2048 + s) * 1024 + h * 64 + d] = f2bf(val);
}

extern "C" void kernel_launch(void* const* d_in, const int* in_sizes, int n_in,
                              void* d_out, int out_size, void* d_ws, size_t ws_size,
                              hipStream_t stream) {
  (void)in_sizes; (void)n_in; (void)out_size; (void)ws_size;
  const float* x    = (const float*)d_in[0];
  const float* Wq   = (const float*)d_in[1];
  const float* Wk   = (const float*)d_in[2];
  const float* Wv   = (const float*)d_in[3];
  const float* Wo   = (const float*)d_in[4];
  const float* gate = (const float*)d_in[5];

  u16* ws    = (u16*)d_ws;
  u16* xbf   = ws;                    // 4096x1024 (dead after QKV gemm)
  u16* wbf   = xbf + 4194304;         // 3072x1024 (Wq|Wk|Wv rows)
  u16* wobf  = wbf + 3145728;         // 1024x1024
  u16* raw   = wobf + 1048576;        // 4096x3072 QKV gemm out (dead after rope+transpose)
  u16* Qsb   = raw + 12582912;        // (B,H,S,64) q/8
  u16* Kbb   = Qsb + 4194304;         // (B,H,S,64)
  u16* K2bb  = Kbb + 4194304;         // (B,H,S,64)
  u16* Vtb   = K2bb + 4194304;        // (B,H,64,S)
  float* Opart = (float*)(Vtb + 4194304);  // 2 x 32 x 1024 x 64 fp32 (16.8 MB)
  float* Lpart = Opart + 4194304;          // 2 x 32 x 1024 fp32
  u16* Q2sb  = xbf;                   // alias: written by rope (after gemm)
  u16* attnb = raw;                   // alias: attn out (first 4.19M u16 of raw)
  float* Opart2 = (float*)(raw + 4194304); // alias: raw tail, 2 x 32 x 512 x 64 fp32 (8.4 MB)
  float* Lpart2 = Opart2 + 2097152;        // 2 x 32 x 512 fp32

  cvt_kernel<<<4096, 256, 0, stream>>>(x, xbf, 1048576);
  cvt_w<<<4096, 256, 0, stream>>>(Wq, Wk, Wv, Wo, wbf, wobf);

  gemm_bt<u16><<<dim3(24, 32), 256, 0, stream>>>(xbf, wbf, raw, 3072, 1024);
  rope_kernel<<<16384, 256, 0, stream>>>(raw, Qsb, Q2sb, Kbb, K2bb);
  transpose_v<<<dim3(32, 32), 256, 0, stream>>>(raw, Vtb);
  attn_kernel<<<dim3(28, 32), 256, 0, stream>>>(Qsb, Q2sb, Kbb, K2bb, Vtb, gate, attnb,
                                                Opart, Lpart, Opart2, Lpart2);
  combine_kernel<<<12288, 256, 0, stream>>>(Opart, Lpart, Opart2, Lpart2, gate, attnb);
  gemm_bt<float><<<dim3(8, 32), 256, 0, stream>>>(attnb, wobf, (float*)d_out, 1024, 1024);
}

// Round 9
// 277.101 us; speedup vs baseline: 1.4397x; 1.2194x over previous
//
#include <hip/hip_runtime.h>

typedef unsigned short u16;
typedef __attribute__((ext_vector_type(4))) unsigned short u16x4;
typedef __attribute__((ext_vector_type(8))) unsigned short u16x8;
typedef __attribute__((ext_vector_type(8))) short s16x8;
typedef __attribute__((ext_vector_type(4))) float f32x4;

__device__ __forceinline__ u16 f2bf(float f) {
  unsigned int u = __float_as_uint(f);
  u += 0x7FFFu + ((u >> 16) & 1u);   // RNE
  return (u16)(u >> 16);
}
__device__ __forceinline__ float bf2f(u16 h) {
  return __uint_as_float(((unsigned int)h) << 16);
}

// async global->LDS, 16B per lane; base = lane0's lds ptr, lane i writes base+i*16B.
__device__ __forceinline__ void gload_lds16(const u16* g, u16* l) {
  __builtin_amdgcn_global_load_lds(
      (const __attribute__((address_space(1))) unsigned int*)(g),
      (__attribute__((address_space(3))) unsigned int*)(l), 16, 0, 0);
}

// ---------------- fp32 -> bf16 convert (x4 vectorized) ----------------
__global__ __launch_bounds__(256) void cvt_kernel(const float* __restrict__ src,
                                                  u16* __restrict__ dst, int n4) {
  int i = blockIdx.x * 256 + threadIdx.x;
  if (i >= n4) return;
  float4 v = reinterpret_cast<const float4*>(src)[i];
  u16x4 o;
  o.x = f2bf(v.x); o.y = f2bf(v.y); o.z = f2bf(v.z); o.w = f2bf(v.w);
  reinterpret_cast<u16x4*>(dst)[i] = o;
}

// all four 1024x1024 weights in one launch
__global__ __launch_bounds__(256) void cvt_w(const float* __restrict__ Wq,
                                             const float* __restrict__ Wk,
                                             const float* __restrict__ Wv,
                                             const float* __restrict__ Wo,
                                             u16* __restrict__ wbf, u16* __restrict__ wobf) {
  int blk = blockIdx.x;           // 0..4095
  int sel = blk >> 10;
  const float* src = (sel == 0) ? Wq : (sel == 1) ? Wk : (sel == 2) ? Wv : Wo;
  u16* dst = (sel < 3) ? (wbf + (size_t)sel * 1048576) : wobf;
  int i = (blk & 1023) * 256 + threadIdx.x;
  float4 v = reinterpret_cast<const float4*>(src)[i];
  u16x4 o;
  o.x = f2bf(v.x); o.y = f2bf(v.y); o.z = f2bf(v.z); o.w = f2bf(v.w);
  reinterpret_cast<u16x4*>(dst)[i] = o;
}

// ---------------- templated GEMM: C[m][n] = sum_k A[m][k]*B[n][k] (B^T input) ----------------
// Block = 2x2 waves; wave tile = (WM*16) x (WN*16). BM = WM*32, BN = WN*32, BK = 32.
// global_load_lds staging, chunk = 16 rows x 32 cols = 512 u16, packed at c*512+lane*8.
__device__ __forceinline__ void store_out(float* p, float v) { *p = v; }
__device__ __forceinline__ void store_out(u16* p, float v) { *p = f2bf(v); }

template <typename OutT, int WM, int WN>
__global__ __launch_bounds__(256) void gemm_bt(const u16* __restrict__ A,
                                               const u16* __restrict__ Bw,
                                               OutT* __restrict__ C, int N, int K) {
  __shared__ u16 As[2 * WM * 512];
  __shared__ u16 Bs[2 * WN * 512];
  const int tid = threadIdx.x;
  const int lane = tid & 63;
  const int wave = tid >> 6;
  const int wm = wave >> 1, wn = wave & 1;
  const int lh = lane & 15, quad = lane >> 4;
  const int q8 = quad * 8;
  const int m0 = blockIdx.y * (WM * 32), n0 = blockIdx.x * (WN * 32);
  constexpr int NCH = 2 * (WM + WN);
  constexpr int PER = NCH / 4;

  f32x4 acc[WM][WN];
#pragma unroll
  for (int i = 0; i < WM; ++i)
#pragma unroll
    for (int j = 0; j < WN; ++j) { acc[i][j][0] = 0.f; acc[i][j][1] = 0.f; acc[i][j][2] = 0.f; acc[i][j][3] = 0.f; }

  const int nkt = K >> 5;
  for (int kt = 0; kt < nkt; ++kt) {
    const int kb = kt * 32;
    __syncthreads();  // prior tile's LDS reads done
#pragma unroll
    for (int i = 0; i < PER; ++i) {
      const int c = wave * PER + i;
      if (c < 2 * WM) {
        gload_lds16(A + (size_t)(m0 + c * 16 + lh) * K + kb + q8, &As[c * 512 + lane * 8]);
      } else {
        const int rb = c - 2 * WM;
        gload_lds16(Bw + (size_t)(n0 + rb * 16 + lh) * K + kb + q8, &Bs[rb * 512 + lane * 8]);
      }
    }
    __syncthreads();  // drains DMA, staged tile visible
    s16x8 af[WM], bf4[WN];
#pragma unroll
    for (int mb = 0; mb < WM; ++mb)
      af[mb] = *reinterpret_cast<const s16x8*>(&As[(wm * WM + mb) * 512 + lane * 8]);
#pragma unroll
    for (int nb = 0; nb < WN; ++nb)
      bf4[nb] = *reinterpret_cast<const s16x8*>(&Bs[(wn * WN + nb) * 512 + lane * 8]);
#pragma unroll
    for (int mb = 0; mb < WM; ++mb)
#pragma unroll
      for (int nb = 0; nb < WN; ++nb)
        acc[mb][nb] = __builtin_amdgcn_mfma_f32_16x16x32_bf16(af[mb], bf4[nb], acc[mb][nb], 0, 0, 0);
  }
#pragma unroll
  for (int mb = 0; mb < WM; ++mb)
#pragma unroll
    for (int nb = 0; nb < WN; ++nb) {
      const int col = n0 + wn * (WN * 16) + nb * 16 + lh;
#pragma unroll
      for (int r = 0; r < 4; ++r) {
        const int row = m0 + wm * (WM * 16) + mb * 16 + quad * 4 + r;
        store_out(&C[(size_t)row * N + col], acc[mb][nb][r]);
      }
    }
}

// ---------------- QKV GEMM with fused RoPE epilogue ----------------
// Same 128x128 body as gemm_bt<.,4,4>; N=3072, K=1024. Epilogue branches on bx:
// bx<8 (Q cols): rope on fp32 acc -> Qs (pre-scaled q/8). bx<16 (K cols): rope ->
// Kb, K2b (e^2). bx>=16 (V cols): plain bf16 store to raw (stride 3072).
// RoPE pairing: within a wave, cols (d, d+32) of a head live in acc[.][nb] and
// acc[.][nb+2] of the SAME lane (d = nb*16+lh for nb in {0,1}).
__global__ __launch_bounds__(256) void qkv_gemm(const u16* __restrict__ A,
                                                const u16* __restrict__ Bw,
                                                u16* __restrict__ raw,
                                                u16* __restrict__ Qs,
                                                u16* __restrict__ Kb,
                                                u16* __restrict__ K2b) {
  __shared__ u16 As[4096];
  __shared__ u16 Bs[4096];
  const int tid = threadIdx.x;
  const int lane = tid & 63;
  const int wave = tid >> 6;
  const int wm = wave >> 1, wn = wave & 1;
  const int lh = lane & 15, quad = lane >> 4;
  const int q8 = quad * 8;
  const int bx = blockIdx.x;
  const int m0 = blockIdx.y * 128, n0 = bx * 128;
  const int K = 1024;

  f32x4 acc[4][4];
#pragma unroll
  for (int i = 0; i < 4; ++i)
#pragma unroll
    for (int j = 0; j < 4; ++j) { acc[i][j][0] = 0.f; acc[i][j][1] = 0.f; acc[i][j][2] = 0.f; acc[i][j][3] = 0.f; }

  for (int kt = 0; kt < 32; ++kt) {
    const int kb = kt * 32;
    __syncthreads();
#pragma unroll
    for (int i = 0; i < 4; ++i) {
      const int c = wave * 4 + i;
      if (c < 8) {
        gload_lds16(A + (size_t)(m0 + c * 16 + lh) * K + kb + q8, &As[c * 512 + lane * 8]);
      } else {
        const int rb = c - 8;
        gload_lds16(Bw + (size_t)(n0 + rb * 16 + lh) * K + kb + q8, &Bs[rb * 512 + lane * 8]);
      }
    }
    __syncthreads();
    s16x8 af[4], bf4[4];
#pragma unroll
    for (int mb = 0; mb < 4; ++mb)
      af[mb] = *reinterpret_cast<const s16x8*>(&As[(wm * 4 + mb) * 512 + lane * 8]);
#pragma unroll
    for (int nb = 0; nb < 4; ++nb)
      bf4[nb] = *reinterpret_cast<const s16x8*>(&Bs[(wn * 4 + nb) * 512 + lane * 8]);
#pragma unroll
    for (int mb = 0; mb < 4; ++mb)
#pragma unroll
      for (int nb = 0; nb < 4; ++nb)
        acc[mb][nb] = __builtin_amdgcn_mfma_f32_16x16x32_bf16(af[mb], bf4[nb], acc[mb][nb], 0, 0, 0);
  }

  if (bx < 16) {
    const bool isQ = (bx < 8);
#pragma unroll
    for (int nb = 0; nb < 2; ++nb) {
      const int d = nb * 16 + lh;                       // 0..31 (first half of head)
      const float invf = __expf((float)d * -0.2878231366f);  // 10000^(-d/32)
      const int col = n0 + wn * 64 + nb * 16 + lh;
      const int ch = col & 1023;                        // col within Q or K block
      const int h = ch >> 6;
#pragma unroll
      for (int mb = 0; mb < 4; ++mb)
#pragma unroll
        for (int r = 0; r < 4; ++r) {
          const int row = m0 + wm * 64 + mb * 16 + quad * 4 + r;
          const int s = row & 2047, b = row >> 11;
          float ang = (float)s * invf;
          float sv, cv;
          __sincosf(ang, &sv, &cv);
          const float v1 = acc[mb][nb][r], v2 = acc[mb][nb + 2][r];
          const float e0 = v1 * cv - v2 * sv;
          const float e1 = v2 * cv + v1 * sv;
          const size_t ofs = (size_t)((b * 16 + h) * 2048 + s) * 64 + d;
          if (isQ) {
            Qs[ofs]      = f2bf(e0 * 0.125f);
            Qs[ofs + 32] = f2bf(e1 * 0.125f);
          } else {
            Kb[ofs]       = f2bf(e0);
            Kb[ofs + 32]  = f2bf(e1);
            K2b[ofs]      = f2bf(e0 * e0);
            K2b[ofs + 32] = f2bf(e1 * e1);
          }
        }
    }
  } else {
#pragma unroll
    for (int mb = 0; mb < 4; ++mb)
#pragma unroll
      for (int nb = 0; nb < 4; ++nb) {
        const int col = n0 + wn * 64 + nb * 16 + lh;
#pragma unroll
        for (int r = 0; r < 4; ++r) {
          const int row = m0 + wm * 64 + mb * 16 + quad * 4 + r;
          raw[(size_t)row * 3072 + col] = f2bf(acc[mb][nb][r]);
        }
      }
  }
}

// ---------------- V transpose: raw V cols -> Vt (B,H,64,S) bf16 ----------------
__global__ __launch_bounds__(256) void transpose_v(const u16* __restrict__ raw,
                                                   u16* __restrict__ Vt) {
  int st = blockIdx.x, bh = blockIdx.y;
  int b = bh >> 4, h = bh & 15;
  __shared__ u16 tile[64 * 72];
  int tid = threadIdx.x;
#pragma unroll
  for (int it = 0; it < 4; ++it) {
    int c = it * 256 + tid;
    int sr = c >> 4, d4 = c & 15;
    u16x4 v = *reinterpret_cast<const u16x4*>(
        raw + (size_t)(b * 2048 + st * 64 + sr) * 3072 + 2048 + h * 64 + d4 * 4);
    *reinterpret_cast<u16x4*>(&tile[sr * 72 + d4 * 4]) = v;
  }
  __syncthreads();
#pragma unroll
  for (int it = 0; it < 4; ++it) {
    int c = it * 256 + tid;
    int dd = c >> 4, s4 = c & 15;
    u16x4 v;
#pragma unroll
    for (int j = 0; j < 4; ++j) v[j] = tile[(s4 * 4 + j) * 72 + dd];
    *reinterpret_cast<u16x4*>(Vt + (size_t)(bh * 64 + dd) * 2048 + st * 64 + s4 * 4) = v;
  }
}

// ---------------- flash-style causal amplified attention (r6 structure) ----------------
// LDS double-buffered K/K2 staging (proven 91us vs 160us barrier-free), fixed-max
// softmax (max=8 folded into acc init), extended split-K: qi>=4 all split in two.
// Q2 fragments DERIVED in registers from Qs: q2 = (q/8)^2 * 0.8 = q^2 * 0.0125.
// grid (28, 32): bx<16: qi=15-(bx>>1) halves -> Opart; bx 16..23: qi=7-((bx-16)>>1)
// halves -> Opart2; bx 24..27: qi=27-bx whole, inline epilogue.
__global__ __launch_bounds__(256, 2) void attn_kernel(const u16* __restrict__ Qs,
                                                      const u16* __restrict__ Kb,
                                                      const u16* __restrict__ K2b,
                                                      const u16* __restrict__ Vt,
                                                      const float* __restrict__ gate,
                                                      u16* __restrict__ attn,
                                                      float* __restrict__ Opart,
                                                      float* __restrict__ Lpart,
                                                      float* __restrict__ Opart2,
                                                      float* __restrict__ Lpart2) {
  const int bx = blockIdx.x;
  int qi, kt0, kt1, half, which;
  bool split;
  if (bx < 16) {
    qi = 15 - (bx >> 1); half = bx & 1; split = true; which = 0;
    const int nk = qi + 1; kt0 = half * nk; kt1 = kt0 + nk - 1;
  } else if (bx < 24) {
    const int t = bx - 16;
    qi = 7 - (t >> 1); half = t & 1; split = true; which = 1;
    const int nk = qi + 1; kt0 = half * nk; kt1 = kt0 + nk - 1;
  } else {
    qi = 27 - bx; split = false; which = 0; half = 0; kt0 = 0; kt1 = 2 * qi + 1;
  }
  const int bh = blockIdx.y;
  const int tid = threadIdx.x, lane = tid & 63, wave = tid >> 6;
  const int lh = lane & 15, quad = lane >> 4;
  const int b = bh >> 4, h = bh & 15;
  __shared__ u16 stageS[2][8192];   // [K chunks: 0..4095 | K2 chunks: 4096..8191], 512 u16/chunk
  __shared__ u16 Pbuf[4][2][1152];  // per (wave, mb): 16 rows x 72
  const int base = qi * 128 + wave * 32;   // wave's first Q row
  const int q8 = quad * 8;

  auto do_stage = [&](int buf, int kt) {
#pragma unroll
    for (int i = 0; i < 4; ++i) {
      const int c = wave * 4 + i;   // 0..15; t2=c>>3 (0=K,1=K2), f=c&7 = kk*4+nb
      const int t2 = c >> 3, f = c & 7, kk = f >> 2, nb = f & 3;
      const u16* src = (t2 ? K2b : Kb) +
          (size_t)(bh * 2048 + kt * 64 + nb * 16 + lh) * 64 + kk * 32 + q8;
      gload_lds16(src, &stageS[buf][t2 * 4096 + f * 512 + lane * 8]);
    }
  };

  // Q fragments (A-layout): m = lh, k = kk*32 + quad*8 + j ; q/8 pre-scaled in memory.
  // q2 = (q/8)^2 * 0.8 derived in registers (= q^2 * lambda/8).
  s16x8 qf[2][2], q2f[2][2];
#pragma unroll
  for (int mb = 0; mb < 2; ++mb) {
    const size_t qoff = (size_t)(bh * 2048 + base + mb * 16 + lh) * 64 + q8;
#pragma unroll
    for (int kk = 0; kk < 2; ++kk) {
      qf[mb][kk] = *reinterpret_cast<const s16x8*>(Qs + qoff + kk * 32);
#pragma unroll
      for (int j = 0; j < 8; ++j) {
        float f = bf2f((u16)qf[mb][kk][j]);
        q2f[mb][kk][j] = (short)f2bf(f * f * 0.8f);
      }
    }
  }

  f32x4 oacc[2][4];
  float lsum[2][4];
#pragma unroll
  for (int mb = 0; mb < 2; ++mb)
#pragma unroll
    for (int nb = 0; nb < 4; ++nb) { oacc[mb][nb][0] = 0.f; oacc[mb][nb][1] = 0.f; oacc[mb][nb][2] = 0.f; oacc[mb][nb][3] = 0.f; }
#pragma unroll
  for (int mb = 0; mb < 2; ++mb)
#pragma unroll
    for (int r = 0; r < 4; ++r) lsum[mb][r] = 0.f;
  float gw[4];
#pragma unroll
  for (int nb = 0; nb < 4; ++nb) gw[nb] = gate[nb * 16 + lh];

  do_stage(0, kt0);
  __syncthreads();  // drain DMA for first tile

  const int wmaxrow = base + 31;
  for (int kt = kt0; kt <= kt1; ++kt) {
    const int p = (kt - kt0) & 1;
    if (kt < kt1) do_stage(1 - p, kt + 1);  // async prefetch, drained at end barrier

    if (kt * 64 <= wmaxrow) {  // wave-uniform skip of fully-masked tiles
      const u16* Ks = stageS[p];
      f32x4 sacc[2][4];
#pragma unroll
      for (int mb = 0; mb < 2; ++mb)
#pragma unroll
        for (int nb = 0; nb < 4; ++nb) { sacc[mb][nb][0] = -8.f; sacc[mb][nb][1] = -8.f; sacc[mb][nb][2] = -8.f; sacc[mb][nb][3] = -8.f; }
#pragma unroll
      for (int nb = 0; nb < 4; ++nb)
#pragma unroll
        for (int kk = 0; kk < 2; ++kk) {
          s16x8 kf  = *reinterpret_cast<const s16x8*>(&Ks[(kk * 4 + nb) * 512 + lane * 8]);
          s16x8 k2f = *reinterpret_cast<const s16x8*>(&Ks[4096 + (kk * 4 + nb) * 512 + lane * 8]);
#pragma unroll
          for (int mb = 0; mb < 2; ++mb) {
            sacc[mb][nb] = __builtin_amdgcn_mfma_f32_16x16x32_bf16(qf[mb][kk],  kf,  sacc[mb][nb], 0, 0, 0);
            sacc[mb][nb] = __builtin_amdgcn_mfma_f32_16x16x32_bf16(q2f[mb][kk], k2f, sacc[mb][nb], 0, 0, 0);
          }
        }
      // V fragments (global; latency hides under exp/pack, L1-shared by 4 waves)
      s16x8 vf[2][4];
#pragma unroll
      for (int kk = 0; kk < 2; ++kk)
#pragma unroll
        for (int nb = 0; nb < 4; ++nb)
          vf[kk][nb] = *reinterpret_cast<const s16x8*>(
              Vt + (size_t)(bh * 64 + nb * 16 + lh) * 2048 + kt * 64 + kk * 32 + q8);

      if (kt * 64 + 63 > base) {  // tiles overlapping the diagonal: elementwise mask
#pragma unroll
        for (int mb = 0; mb < 2; ++mb)
#pragma unroll
          for (int nb = 0; nb < 4; ++nb) {
            const int colg = kt * 64 + nb * 16 + lh;
#pragma unroll
            for (int r = 0; r < 4; ++r) {
              const int rowg = base + mb * 16 + quad * 4 + r;
              if (colg > rowg) sacc[mb][nb][r] = -1e9f;
            }
          }
      }
      // p = exp(s - 8); per-lane row-sum partials (reduced once after the loop)
#pragma unroll
      for (int mb = 0; mb < 2; ++mb)
#pragma unroll
        for (int nb = 0; nb < 4; ++nb)
#pragma unroll
          for (int r = 0; r < 4; ++r) {
            float pv = __expf(sacc[mb][nb][r]);
            lsum[mb][r] += pv;
            Pbuf[wave][mb][(quad * 4 + r) * 72 + nb * 16 + lh] = f2bf(pv);
          }
      // PV: P through LDS (C-layout -> A-layout), wave-private, no barrier
#pragma unroll
      for (int mb = 0; mb < 2; ++mb)
#pragma unroll
        for (int kk = 0; kk < 2; ++kk) {
          s16x8 pf = *reinterpret_cast<const s16x8*>(&Pbuf[wave][mb][lh * 72 + kk * 32 + q8]);
#pragma unroll
          for (int nb = 0; nb < 4; ++nb)
            oacc[mb][nb] = __builtin_amdgcn_mfma_f32_16x16x32_bf16(pf, vf[kk][nb], oacc[mb][nb], 0, 0, 0);
        }
    }
    __syncthreads();  // all waves done with stageS[p]; prefetch for kt+1 drained
  }
  // reduce row sums across the 16 lanes holding each row
#pragma unroll
  for (int mb = 0; mb < 2; ++mb)
#pragma unroll
    for (int r = 0; r < 4; ++r) {
      float rs = lsum[mb][r];
#pragma unroll
      for (int off = 1; off < 16; off <<= 1) rs += __shfl_xor(rs, off);
      lsum[mb][r] = rs;
    }
  if (split) {
    // unnormalized partials to ws (fp32)
#pragma unroll
    for (int mb = 0; mb < 2; ++mb)
#pragma unroll
      for (int r = 0; r < 4; ++r) {
        const int rowg = base + mb * 16 + quad * 4 + r;
        if (which == 0) {
          const size_t orow = (size_t)half * 32768 + bh * 1024 + (rowg - 1024);
          if (lh == 0) Lpart[orow] = lsum[mb][r];
#pragma unroll
          for (int nb = 0; nb < 4; ++nb)
            Opart[orow * 64 + nb * 16 + lh] = oacc[mb][nb][r];
        } else {
          const size_t orow = (size_t)half * 16384 + bh * 512 + (rowg - 512);
          if (lh == 0) Lpart2[orow] = lsum[mb][r];
#pragma unroll
          for (int nb = 0; nb < 4; ++nb)
            Opart2[orow * 64 + nb * 16 + lh] = oacc[mb][nb][r];
        }
      }
  } else {
    // finalize: o/l, epilogue o + 0.05*o^2*g[d] (out2==out1 identity)
#pragma unroll
    for (int mb = 0; mb < 2; ++mb)
#pragma unroll
      for (int r = 0; r < 4; ++r) {
        const float invl = 1.0f / lsum[mb][r];
        const int rows = base + mb * 16 + quad * 4 + r;
#pragma unroll
        for (int nb = 0; nb < 4; ++nb) {
          float o = oacc[mb][nb][r] * invl;
          float val = o + 0.05f * o * o * gw[nb];
          attn[(size_t)(b * 2048 + rows) * 1024 + h * 64 + nb * 16 + lh] = f2bf(val);
        }
      }
  }
}

// ---------------- combine split-K partials (rows 512..2047) ----------------
__global__ __launch_bounds__(256) void combine_kernel(const float* __restrict__ Opart,
                                                      const float* __restrict__ Lpart,
                                                      const float* __restrict__ Opart2,
                                                      const float* __restrict__ Lpart2,
                                                      const float* __restrict__ gate,
                                                      u16* __restrict__ attn) {
  int idx = blockIdx.x * 256 + threadIdx.x;   // 0 .. 3145727
  int d = idx & 63;
  int r_all = idx >> 6;
  float o, l;
  int bh, s;
  if (r_all < 32768) {            // rows s >= 1024 (qi >= 8)
    o = Opart[idx] + Opart[idx + 2097152];
    l = Lpart[r_all] + Lpart[r_all + 32768];
    bh = r_all >> 10; s = 1024 + (r_all & 1023);
  } else {                        // rows 512..1023 (qi 4..7)
    const int r2 = r_all - 32768;
    const int i2 = idx - 2097152;
    o = Opart2[i2] + Opart2[i2 + 1048576];
    l = Lpart2[r2] + Lpart2[r2 + 16384];
    bh = r2 >> 9; s = 512 + (r2 & 511);
  }
  o /= l;
  float val = o + 0.05f * o * o * gate[d];
  int b = bh >> 4, h = bh & 15;
  attn[(size_t)(b * 2048 + s) * 1024 + h * 64 + d] = f2bf(val);
}

extern "C" void kernel_launch(void* const* d_in, const int* in_sizes, int n_in,
                              void* d_out, int out_size, void* d_ws, size_t ws_size,
                              hipStream_t stream) {
  (void)in_sizes; (void)n_in; (void)out_size; (void)ws_size;
  const float* x    = (const float*)d_in[0];
  const float* Wq   = (const float*)d_in[1];
  const float* Wk   = (const float*)d_in[2];
  const float* Wv   = (const float*)d_in[3];
  const float* Wo   = (const float*)d_in[4];
  const float* gate = (const float*)d_in[5];

  u16* ws    = (u16*)d_ws;
  u16* xbf   = ws;                    // 4096x1024 bf16 x (input to qkv_gemm)
  u16* wbf   = xbf + 4194304;         // 3072x1024 (Wq|Wk|Wv rows)
  u16* wobf  = wbf + 3145728;         // 1024x1024
  u16* raw   = wobf + 1048576;        // 4096x3072; only V cols written (dead after transpose)
  u16* Qsb   = raw + 12582912;        // (B,H,S,64) q/8
  u16* Kbb   = Qsb + 4194304;         // (B,H,S,64)
  u16* K2bb  = Kbb + 4194304;         // (B,H,S,64)
  u16* Vtb   = K2bb + 4194304;        // (B,H,64,S)
  float* Opart = (float*)(Vtb + 4194304);  // 2 x 32 x 1024 x 64 fp32 (16.8 MB)
  float* Lpart = Opart + 4194304;          // 2 x 32 x 1024 fp32
  u16* attnb = raw;                   // alias: attn out (first 8.4 MB of raw)
  float* Opart2 = (float*)(raw + 4194304); // alias: raw tail, 2 x 32 x 512 x 64 fp32 (8.4 MB)
  float* Lpart2 = Opart2 + 2097152;        // 2 x 32 x 512 fp32

  cvt_kernel<<<4096, 256, 0, stream>>>(x, xbf, 1048576);
  cvt_w<<<4096, 256, 0, stream>>>(Wq, Wk, Wv, Wo, wbf, wobf);

  qkv_gemm<<<dim3(24, 32), 256, 0, stream>>>(xbf, wbf, raw, Qsb, Kbb, K2bb);
  transpose_v<<<dim3(32, 32), 256, 0, stream>>>(raw, Vtb);
  attn_kernel<<<dim3(28, 32), 256, 0, stream>>>(Qsb, Kbb, K2bb, Vtb, gate, attnb,
                                                Opart, Lpart, Opart2, Lpart2);
  combine_kernel<<<12288, 256, 0, stream>>>(Opart, Lpart, Opart2, Lpart2, gate, attnb);
  gemm_bt<float, 4, 2><<<dim3(16, 32), 256, 0, stream>>>(attnb, wobf, (float*)d_out, 1024, 1024);
}

// Round 10
// 274.313 us; speedup vs baseline: 1.4543x; 1.0102x over previous
//
#include <hip/hip_runtime.h>

typedef unsigned short u16;
typedef __attribute__((ext_vector_type(4))) unsigned short u16x4;
typedef __attribute__((ext_vector_type(8))) unsigned short u16x8;
typedef __attribute__((ext_vector_type(8))) short s16x8;
typedef __attribute__((ext_vector_type(4))) float f32x4;

__device__ __forceinline__ u16 f2bf(float f) {
  unsigned int u = __float_as_uint(f);
  u += 0x7FFFu + ((u >> 16) & 1u);   // RNE
  return (u16)(u >> 16);
}
__device__ __forceinline__ float bf2f(u16 h) {
  return __uint_as_float(((unsigned int)h) << 16);
}

// async global->LDS, 16B per lane; base = lane0's lds ptr, lane i writes base+i*16B.
__device__ __forceinline__ void gload_lds16(const u16* g, u16* l) {
  __builtin_amdgcn_global_load_lds(
      (const __attribute__((address_space(1))) unsigned int*)(g),
      (__attribute__((address_space(3))) unsigned int*)(l), 16, 0, 0);
}

// ---------------- fp32 -> bf16 convert (x4 vectorized) ----------------
__global__ __launch_bounds__(256) void cvt_kernel(const float* __restrict__ src,
                                                  u16* __restrict__ dst, int n4) {
  int i = blockIdx.x * 256 + threadIdx.x;
  if (i >= n4) return;
  float4 v = reinterpret_cast<const float4*>(src)[i];
  u16x4 o;
  o.x = f2bf(v.x); o.y = f2bf(v.y); o.z = f2bf(v.z); o.w = f2bf(v.w);
  reinterpret_cast<u16x4*>(dst)[i] = o;
}

// all four 1024x1024 weights in one launch
__global__ __launch_bounds__(256) void cvt_w(const float* __restrict__ Wq,
                                             const float* __restrict__ Wk,
                                             const float* __restrict__ Wv,
                                             const float* __restrict__ Wo,
                                             u16* __restrict__ wbf, u16* __restrict__ wobf) {
  int blk = blockIdx.x;           // 0..4095
  int sel = blk >> 10;
  const float* src = (sel == 0) ? Wq : (sel == 1) ? Wk : (sel == 2) ? Wv : Wo;
  u16* dst = (sel < 3) ? (wbf + (size_t)sel * 1048576) : wobf;
  int i = (blk & 1023) * 256 + threadIdx.x;
  float4 v = reinterpret_cast<const float4*>(src)[i];
  u16x4 o;
  o.x = f2bf(v.x); o.y = f2bf(v.y); o.z = f2bf(v.z); o.w = f2bf(v.w);
  reinterpret_cast<u16x4*>(dst)[i] = o;
}

// ---------------- templated GEMM, BK=64: C[m][n] = sum_k A[m][k]*B[n][k] (B^T) ----------------
// Block = 2x2 waves; wave tile = (WM*16) x (WN*16). BM=WM*32, BN=WN*32, BK=64.
// Chunk = 16 rows x 32 k-cols = 512 u16 (one global_load_lds16). Per 16-row group:
// 2 chunks (k-halves). 2x fewer barrier drains per K than BK=32 (the m97-class stall).
__device__ __forceinline__ void store_out(float* p, float v) { *p = v; }
__device__ __forceinline__ void store_out(u16* p, float v) { *p = f2bf(v); }

template <typename OutT, int WM, int WN>
__global__ __launch_bounds__(256) void gemm_bt(const u16* __restrict__ A,
                                               const u16* __restrict__ Bw,
                                               OutT* __restrict__ C, int N, int K) {
  __shared__ u16 As[WM * 2048];
  __shared__ u16 Bs[WN * 2048];
  const int tid = threadIdx.x;
  const int lane = tid & 63;
  const int wave = tid >> 6;
  const int wm = wave >> 1, wn = wave & 1;
  const int lh = lane & 15, quad = lane >> 4;
  const int q8 = quad * 8;
  const int m0 = blockIdx.y * (WM * 32), n0 = blockIdx.x * (WN * 32);
  constexpr int NCH = 4 * (WM + WN);
  constexpr int PER = NCH / 4;

  f32x4 acc[WM][WN];
#pragma unroll
  for (int i = 0; i < WM; ++i)
#pragma unroll
    for (int j = 0; j < WN; ++j) { acc[i][j][0] = 0.f; acc[i][j][1] = 0.f; acc[i][j][2] = 0.f; acc[i][j][3] = 0.f; }

  const int nkt = K >> 6;
  for (int kt = 0; kt < nkt; ++kt) {
    const int kb = kt * 64;
    __syncthreads();  // prior tile's LDS reads done
#pragma unroll
    for (int i = 0; i < PER; ++i) {
      const int c = wave * PER + i;
      if (c < 4 * WM) {
        const int rb = c >> 1, kk2 = c & 1;
        gload_lds16(A + (size_t)(m0 + rb * 16 + lh) * K + kb + kk2 * 32 + q8,
                    &As[c * 512 + lane * 8]);
      } else {
        const int cb = c - 4 * WM;
        const int rb = cb >> 1, kk2 = cb & 1;
        gload_lds16(Bw + (size_t)(n0 + rb * 16 + lh) * K + kb + kk2 * 32 + q8,
                    &Bs[cb * 512 + lane * 8]);
      }
    }
    __syncthreads();  // drains DMA, staged tile visible
#pragma unroll
    for (int kk2 = 0; kk2 < 2; ++kk2) {
      s16x8 af[WM], bf4[WN];
#pragma unroll
      for (int mb = 0; mb < WM; ++mb)
        af[mb] = *reinterpret_cast<const s16x8*>(&As[((wm * WM + mb) * 2 + kk2) * 512 + lane * 8]);
#pragma unroll
      for (int nb = 0; nb < WN; ++nb)
        bf4[nb] = *reinterpret_cast<const s16x8*>(&Bs[((wn * WN + nb) * 2 + kk2) * 512 + lane * 8]);
#pragma unroll
      for (int mb = 0; mb < WM; ++mb)
#pragma unroll
        for (int nb = 0; nb < WN; ++nb)
          acc[mb][nb] = __builtin_amdgcn_mfma_f32_16x16x32_bf16(af[mb], bf4[nb], acc[mb][nb], 0, 0, 0);
    }
  }
#pragma unroll
  for (int mb = 0; mb < WM; ++mb)
#pragma unroll
    for (int nb = 0; nb < WN; ++nb) {
      const int col = n0 + wn * (WN * 16) + nb * 16 + lh;
#pragma unroll
      for (int r = 0; r < 4; ++r) {
        const int row = m0 + wm * (WM * 16) + mb * 16 + quad * 4 + r;
        store_out(&C[(size_t)row * N + col], acc[mb][nb][r]);
      }
    }
}

// ---------------- QKV GEMM (BK=64) with fused RoPE epilogue ----------------
// 128x128 tile, N=3072, K=1024, nkt=16. Epilogue: bx<8 Q cols -> rope -> Qs (q/8);
// bx<16 K cols -> rope -> Kb,K2b; bx>=16 V cols -> raw. Pairing: cols (d, d+32) of
// a head live in acc[.][nb] / acc[.][nb+2] of the SAME lane (d = nb*16+lh, nb<2).
__global__ __launch_bounds__(256) void qkv_gemm(const u16* __restrict__ A,
                                                const u16* __restrict__ Bw,
                                                u16* __restrict__ raw,
                                                u16* __restrict__ Qs,
                                                u16* __restrict__ Kb,
                                                u16* __restrict__ K2b) {
  __shared__ u16 As[8192];
  __shared__ u16 Bs[8192];
  const int tid = threadIdx.x;
  const int lane = tid & 63;
  const int wave = tid >> 6;
  const int wm = wave >> 1, wn = wave & 1;
  const int lh = lane & 15, quad = lane >> 4;
  const int q8 = quad * 8;
  const int bx = blockIdx.x;
  const int m0 = blockIdx.y * 128, n0 = bx * 128;
  const int K = 1024;

  f32x4 acc[4][4];
#pragma unroll
  for (int i = 0; i < 4; ++i)
#pragma unroll
    for (int j = 0; j < 4; ++j) { acc[i][j][0] = 0.f; acc[i][j][1] = 0.f; acc[i][j][2] = 0.f; acc[i][j][3] = 0.f; }

  for (int kt = 0; kt < 16; ++kt) {
    const int kb = kt * 64;
    __syncthreads();
#pragma unroll
    for (int i = 0; i < 8; ++i) {
      const int c = wave * 8 + i;   // 0..31: 0-15 A chunks, 16-31 B chunks
      if (c < 16) {
        const int rb = c >> 1, kk2 = c & 1;
        gload_lds16(A + (size_t)(m0 + rb * 16 + lh) * K + kb + kk2 * 32 + q8,
                    &As[c * 512 + lane * 8]);
      } else {
        const int cb = c - 16;
        const int rb = cb >> 1, kk2 = cb & 1;
        gload_lds16(Bw + (size_t)(n0 + rb * 16 + lh) * K + kb + kk2 * 32 + q8,
                    &Bs[cb * 512 + lane * 8]);
      }
    }
    __syncthreads();
#pragma unroll
    for (int kk2 = 0; kk2 < 2; ++kk2) {
      s16x8 af[4], bf4[4];
#pragma unroll
      for (int mb = 0; mb < 4; ++mb)
        af[mb] = *reinterpret_cast<const s16x8*>(&As[((wm * 4 + mb) * 2 + kk2) * 512 + lane * 8]);
#pragma unroll
      for (int nb = 0; nb < 4; ++nb)
        bf4[nb] = *reinterpret_cast<const s16x8*>(&Bs[((wn * 4 + nb) * 2 + kk2) * 512 + lane * 8]);
#pragma unroll
      for (int mb = 0; mb < 4; ++mb)
#pragma unroll
        for (int nb = 0; nb < 4; ++nb)
          acc[mb][nb] = __builtin_amdgcn_mfma_f32_16x16x32_bf16(af[mb], bf4[nb], acc[mb][nb], 0, 0, 0);
    }
  }

  if (bx < 16) {
    const bool isQ = (bx < 8);
#pragma unroll
    for (int nb = 0; nb < 2; ++nb) {
      const int d = nb * 16 + lh;                       // 0..31 (first half of head)
      const float invf = __expf((float)d * -0.2878231366f);  // 10000^(-d/32)
      const int col = n0 + wn * 64 + nb * 16 + lh;
      const int ch = col & 1023;                        // col within Q or K block
      const int h = ch >> 6;
#pragma unroll
      for (int mb = 0; mb < 4; ++mb)
#pragma unroll
        for (int r = 0; r < 4; ++r) {
          const int row = m0 + wm * 64 + mb * 16 + quad * 4 + r;
          const int s = row & 2047, b = row >> 11;
          float ang = (float)s * invf;
          float sv, cv;
          __sincosf(ang, &sv, &cv);
          const float v1 = acc[mb][nb][r], v2 = acc[mb][nb + 2][r];
          const float e0 = v1 * cv - v2 * sv;
          const float e1 = v2 * cv + v1 * sv;
          const size_t ofs = (size_t)((b * 16 + h) * 2048 + s) * 64 + d;
          if (isQ) {
            Qs[ofs]      = f2bf(e0 * 0.125f);
            Qs[ofs + 32] = f2bf(e1 * 0.125f);
          } else {
            Kb[ofs]       = f2bf(e0);
            Kb[ofs + 32]  = f2bf(e1);
            K2b[ofs]      = f2bf(e0 * e0);
            K2b[ofs + 32] = f2bf(e1 * e1);
          }
        }
    }
  } else {
#pragma unroll
    for (int mb = 0; mb < 4; ++mb)
#pragma unroll
      for (int nb = 0; nb < 4; ++nb) {
        const int col = n0 + wn * 64 + nb * 16 + lh;
#pragma unroll
        for (int r = 0; r < 4; ++r) {
          const int row = m0 + wm * 64 + mb * 16 + quad * 4 + r;
          raw[(size_t)row * 3072 + col] = f2bf(acc[mb][nb][r]);
        }
      }
  }
}

// ---------------- V transpose: raw V cols -> Vt (B,H,64,S) bf16 ----------------
__global__ __launch_bounds__(256) void transpose_v(const u16* __restrict__ raw,
                                                   u16* __restrict__ Vt) {
  int st = blockIdx.x, bh = blockIdx.y;
  int b = bh >> 4, h = bh & 15;
  __shared__ u16 tile[64 * 72];
  int tid = threadIdx.x;
#pragma unroll
  for (int it = 0; it < 4; ++it) {
    int c = it * 256 + tid;
    int sr = c >> 4, d4 = c & 15;
    u16x4 v = *reinterpret_cast<const u16x4*>(
        raw + (size_t)(b * 2048 + st * 64 + sr) * 3072 + 2048 + h * 64 + d4 * 4);
    *reinterpret_cast<u16x4*>(&tile[sr * 72 + d4 * 4]) = v;
  }
  __syncthreads();
#pragma unroll
  for (int it = 0; it < 4; ++it) {
    int c = it * 256 + tid;
    int dd = c >> 4, s4 = c & 15;
    u16x4 v;
#pragma unroll
    for (int j = 0; j < 4; ++j) v[j] = tile[(s4 * 4 + j) * 72 + dd];
    *reinterpret_cast<u16x4*>(Vt + (size_t)(bh * 64 + dd) * 2048 + st * 64 + s4 * 4) = v;
  }
}

// ---------------- flash-style causal amplified attention (r6 structure) ----------------
// LDS double-buffered K/K2 staging, fixed-max softmax (max=8 in acc init), split-K
// for qi>=4. Q2 derived in registers: q2 = (q/8)^2 * 0.8.
// grid (28, 32): bx<16: qi=15-(bx>>1) halves -> Opart; bx 16..23: qi=7-((bx-16)>>1)
// halves -> Opart2; bx 24..27: qi=27-bx whole, inline epilogue.
__global__ __launch_bounds__(256, 2) void attn_kernel(const u16* __restrict__ Qs,
                                                      const u16* __restrict__ Kb,
                                                      const u16* __restrict__ K2b,
                                                      const u16* __restrict__ Vt,
                                                      const float* __restrict__ gate,
                                                      u16* __restrict__ attn,
                                                      float* __restrict__ Opart,
                                                      float* __restrict__ Lpart,
                                                      float* __restrict__ Opart2,
                                                      float* __restrict__ Lpart2) {
  const int bx = blockIdx.x;
  int qi, kt0, kt1, half, which;
  bool split;
  if (bx < 16) {
    qi = 15 - (bx >> 1); half = bx & 1; split = true; which = 0;
    const int nk = qi + 1; kt0 = half * nk; kt1 = kt0 + nk - 1;
  } else if (bx < 24) {
    const int t = bx - 16;
    qi = 7 - (t >> 1); half = t & 1; split = true; which = 1;
    const int nk = qi + 1; kt0 = half * nk; kt1 = kt0 + nk - 1;
  } else {
    qi = 27 - bx; split = false; which = 0; half = 0; kt0 = 0; kt1 = 2 * qi + 1;
  }
  const int bh = blockIdx.y;
  const int tid = threadIdx.x, lane = tid & 63, wave = tid >> 6;
  const int lh = lane & 15, quad = lane >> 4;
  const int b = bh >> 4, h = bh & 15;
  __shared__ u16 stageS[2][8192];   // [K chunks: 0..4095 | K2 chunks: 4096..8191], 512 u16/chunk
  __shared__ u16 Pbuf[4][2][1152];  // per (wave, mb): 16 rows x 72
  const int base = qi * 128 + wave * 32;   // wave's first Q row
  const int q8 = quad * 8;

  auto do_stage = [&](int buf, int kt) {
#pragma unroll
    for (int i = 0; i < 4; ++i) {
      const int c = wave * 4 + i;   // 0..15; t2=c>>3 (0=K,1=K2), f=c&7 = kk*4+nb
      const int t2 = c >> 3, f = c & 7, kk = f >> 2, nb = f & 3;
      const u16* src = (t2 ? K2b : Kb) +
          (size_t)(bh * 2048 + kt * 64 + nb * 16 + lh) * 64 + kk * 32 + q8;
      gload_lds16(src, &stageS[buf][t2 * 4096 + f * 512 + lane * 8]);
    }
  };

  // Q fragments (A-layout): m = lh, k = kk*32 + quad*8 + j ; q/8 pre-scaled in memory.
  s16x8 qf[2][2], q2f[2][2];
#pragma unroll
  for (int mb = 0; mb < 2; ++mb) {
    const size_t qoff = (size_t)(bh * 2048 + base + mb * 16 + lh) * 64 + q8;
#pragma unroll
    for (int kk = 0; kk < 2; ++kk) {
      qf[mb][kk] = *reinterpret_cast<const s16x8*>(Qs + qoff + kk * 32);
#pragma unroll
      for (int j = 0; j < 8; ++j) {
        float f = bf2f((u16)qf[mb][kk][j]);
        q2f[mb][kk][j] = (short)f2bf(f * f * 0.8f);
      }
    }
  }

  f32x4 oacc[2][4];
  float lsum[2][4];
#pragma unroll
  for (int mb = 0; mb < 2; ++mb)
#pragma unroll
    for (int nb = 0; nb < 4; ++nb) { oacc[mb][nb][0] = 0.f; oacc[mb][nb][1] = 0.f; oacc[mb][nb][2] = 0.f; oacc[mb][nb][3] = 0.f; }
#pragma unroll
  for (int mb = 0; mb < 2; ++mb)
#pragma unroll
    for (int r = 0; r < 4; ++r) lsum[mb][r] = 0.f;
  float gw[4];
#pragma unroll
  for (int nb = 0; nb < 4; ++nb) gw[nb] = gate[nb * 16 + lh];

  do_stage(0, kt0);
  __syncthreads();  // drain DMA for first tile

  const int wmaxrow = base + 31;
  for (int kt = kt0; kt <= kt1; ++kt) {
    const int p = (kt - kt0) & 1;
    if (kt < kt1) do_stage(1 - p, kt + 1);  // async prefetch, drained at end barrier

    if (kt * 64 <= wmaxrow) {  // wave-uniform skip of fully-masked tiles
      const u16* Ks = stageS[p];
      f32x4 sacc[2][4];
#pragma unroll
      for (int mb = 0; mb < 2; ++mb)
#pragma unroll
        for (int nb = 0; nb < 4; ++nb) { sacc[mb][nb][0] = -8.f; sacc[mb][nb][1] = -8.f; sacc[mb][nb][2] = -8.f; sacc[mb][nb][3] = -8.f; }
#pragma unroll
      for (int nb = 0; nb < 4; ++nb)
#pragma unroll
        for (int kk = 0; kk < 2; ++kk) {
          s16x8 kf  = *reinterpret_cast<const s16x8*>(&Ks[(kk * 4 + nb) * 512 + lane * 8]);
          s16x8 k2f = *reinterpret_cast<const s16x8*>(&Ks[4096 + (kk * 4 + nb) * 512 + lane * 8]);
#pragma unroll
          for (int mb = 0; mb < 2; ++mb) {
            sacc[mb][nb] = __builtin_amdgcn_mfma_f32_16x16x32_bf16(qf[mb][kk],  kf,  sacc[mb][nb], 0, 0, 0);
            sacc[mb][nb] = __builtin_amdgcn_mfma_f32_16x16x32_bf16(q2f[mb][kk], k2f, sacc[mb][nb], 0, 0, 0);
          }
        }
      // V fragments (global; latency hides under exp/pack, L1-shared by 4 waves)
      s16x8 vf[2][4];
#pragma unroll
      for (int kk = 0; kk < 2; ++kk)
#pragma unroll
        for (int nb = 0; nb < 4; ++nb)
          vf[kk][nb] = *reinterpret_cast<const s16x8*>(
              Vt + (size_t)(bh * 64 + nb * 16 + lh) * 2048 + kt * 64 + kk * 32 + q8);

      if (kt * 64 + 63 > base) {  // tiles overlapping the diagonal: elementwise mask
#pragma unroll
        for (int mb = 0; mb < 2; ++mb)
#pragma unroll
          for (int nb = 0; nb < 4; ++nb) {
            const int colg = kt * 64 + nb * 16 + lh;
#pragma unroll
            for (int r = 0; r < 4; ++r) {
              const int rowg = base + mb * 16 + quad * 4 + r;
              if (colg > rowg) sacc[mb][nb][r] = -1e9f;
            }
          }
      }
      // p = exp(s - 8); per-lane row-sum partials (reduced once after the loop)
#pragma unroll
      for (int mb = 0; mb < 2; ++mb)
#pragma unroll
        for (int nb = 0; nb < 4; ++nb)
#pragma unroll
          for (int r = 0; r < 4; ++r) {
            float pv = __expf(sacc[mb][nb][r]);
            lsum[mb][r] += pv;
            Pbuf[wave][mb][(quad * 4 + r) * 72 + nb * 16 + lh] = f2bf(pv);
          }
      // PV: P through LDS (C-layout -> A-layout), wave-private, no barrier
#pragma unroll
      for (int mb = 0; mb < 2; ++mb)
#pragma unroll
        for (int kk = 0; kk < 2; ++kk) {
          s16x8 pf = *reinterpret_cast<const s16x8*>(&Pbuf[wave][mb][lh * 72 + kk * 32 + q8]);
#pragma unroll
          for (int nb = 0; nb < 4; ++nb)
            oacc[mb][nb] = __builtin_amdgcn_mfma_f32_16x16x32_bf16(pf, vf[kk][nb], oacc[mb][nb], 0, 0, 0);
        }
    }
    __syncthreads();  // all waves done with stageS[p]; prefetch for kt+1 drained
  }
  // reduce row sums across the 16 lanes holding each row
#pragma unroll
  for (int mb = 0; mb < 2; ++mb)
#pragma unroll
    for (int r = 0; r < 4; ++r) {
      float rs = lsum[mb][r];
#pragma unroll
      for (int off = 1; off < 16; off <<= 1) rs += __shfl_xor(rs, off);
      lsum[mb][r] = rs;
    }
  if (split) {
    // unnormalized partials to ws (fp32)
#pragma unroll
    for (int mb = 0; mb < 2; ++mb)
#pragma unroll
      for (int r = 0; r < 4; ++r) {
        const int rowg = base + mb * 16 + quad * 4 + r;
        if (which == 0) {
          const size_t orow = (size_t)half * 32768 + bh * 1024 + (rowg - 1024);
          if (lh == 0) Lpart[orow] = lsum[mb][r];
#pragma unroll
          for (int nb = 0; nb < 4; ++nb)
            Opart[orow * 64 + nb * 16 + lh] = oacc[mb][nb][r];
        } else {
          const size_t orow = (size_t)half * 16384 + bh * 512 + (rowg - 512);
          if (lh == 0) Lpart2[orow] = lsum[mb][r];
#pragma unroll
          for (int nb = 0; nb < 4; ++nb)
            Opart2[orow * 64 + nb * 16 + lh] = oacc[mb][nb][r];
        }
      }
  } else {
    // finalize: o/l, epilogue o + 0.05*o^2*g[d] (out2==out1 identity)
#pragma unroll
    for (int mb = 0; mb < 2; ++mb)
#pragma unroll
      for (int r = 0; r < 4; ++r) {
        const float invl = 1.0f / lsum[mb][r];
        const int rows = base + mb * 16 + quad * 4 + r;
#pragma unroll
        for (int nb = 0; nb < 4; ++nb) {
          float o = oacc[mb][nb][r] * invl;
          float val = o + 0.05f * o * o * gw[nb];
          attn[(size_t)(b * 2048 + rows) * 1024 + h * 64 + nb * 16 + lh] = f2bf(val);
        }
      }
  }
}

// ---------------- combine split-K partials (rows 512..2047) ----------------
__global__ __launch_bounds__(256) void combine_kernel(const float* __restrict__ Opart,
                                                      const float* __restrict__ Lpart,
                                                      const float* __restrict__ Opart2,
                                                      const float* __restrict__ Lpart2,
                                                      const float* __restrict__ gate,
                                                      u16* __restrict__ attn) {
  int idx = blockIdx.x * 256 + threadIdx.x;   // 0 .. 3145727
  int d = idx & 63;
  int r_all = idx >> 6;
  float o, l;
  int bh, s;
  if (r_all < 32768) {            // rows s >= 1024 (qi >= 8)
    o = Opart[idx] + Opart[idx + 2097152];
    l = Lpart[r_all] + Lpart[r_all + 32768];
    bh = r_all >> 10; s = 1024 + (r_all & 1023);
  } else {                        // rows 512..1023 (qi 4..7)
    const int r2 = r_all - 32768;
    const int i2 = idx - 2097152;
    o = Opart2[i2] + Opart2[i2 + 1048576];
    l = Lpart2[r2] + Lpart2[r2 + 16384];
    bh = r2 >> 9; s = 512 + (r2 & 511);
  }
  o /= l;
  float val = o + 0.05f * o * o * gate[d];
  int b = bh >> 4, h = bh & 15;
  attn[(size_t)(b * 2048 + s) * 1024 + h * 64 + d] = f2bf(val);
}

extern "C" void kernel_launch(void* const* d_in, const int* in_sizes, int n_in,
                              void* d_out, int out_size, void* d_ws, size_t ws_size,
                              hipStream_t stream) {
  (void)in_sizes; (void)n_in; (void)out_size; (void)ws_size;
  const float* x    = (const float*)d_in[0];
  const float* Wq   = (const float*)d_in[1];
  const float* Wk   = (const float*)d_in[2];
  const float* Wv   = (const float*)d_in[3];
  const float* Wo   = (const float*)d_in[4];
  const float* gate = (const float*)d_in[5];

  u16* ws    = (u16*)d_ws;
  u16* xbf   = ws;                    // 4096x1024 bf16 x (input to qkv_gemm)
  u16* wbf   = xbf + 4194304;         // 3072x1024 (Wq|Wk|Wv rows)
  u16* wobf  = wbf + 3145728;         // 1024x1024
  u16* raw   = wobf + 1048576;        // 4096x3072; only V cols written (dead after transpose)
  u16* Qsb   = raw + 12582912;        // (B,H,S,64) q/8
  u16* Kbb   = Qsb + 4194304;         // (B,H,S,64)
  u16* K2bb  = Kbb + 4194304;         // (B,H,S,64)
  u16* Vtb   = K2bb + 4194304;        // (B,H,64,S)
  float* Opart = (float*)(Vtb + 4194304);  // 2 x 32 x 1024 x 64 fp32 (16.8 MB)
  float* Lpart = Opart + 4194304;          // 2 x 32 x 1024 fp32
  u16* attnb = raw;                   // alias: attn out (first 8.4 MB of raw)
  float* Opart2 = (float*)(raw + 4194304); // alias: raw tail, 2 x 32 x 512 x 64 fp32 (8.4 MB)
  float* Lpart2 = Opart2 + 2097152;        // 2 x 32 x 512 fp32

  cvt_kernel<<<4096, 256, 0, stream>>>(x, xbf, 1048576);
  cvt_w<<<4096, 256, 0, stream>>>(Wq, Wk, Wv, Wo, wbf, wobf);

  qkv_gemm<<<dim3(24, 32), 256, 0, stream>>>(xbf, wbf, raw, Qsb, Kbb, K2bb);
  transpose_v<<<dim3(32, 32), 256, 0, stream>>>(raw, Vtb);
  attn_kernel<<<dim3(28, 32), 256, 0, stream>>>(Qsb, Kbb, K2bb, Vtb, gate, attnb,
                                                Opart, Lpart, Opart2, Lpart2);
  combine_kernel<<<12288, 256, 0, stream>>>(Opart, Lpart, Opart2, Lpart2, gate, attnb);
  gemm_bt<float, 4, 2><<<dim3(16, 32), 256, 0, stream>>>(attnb, wobf, (float*)d_out, 1024, 1024);
}

// Round 11
// 257.674 us; speedup vs baseline: 1.5483x; 1.0646x over previous
//
#include <hip/hip_runtime.h>

typedef unsigned short u16;
typedef __attribute__((ext_vector_type(4))) unsigned short u16x4;
typedef __attribute__((ext_vector_type(8))) unsigned short u16x8;
typedef __attribute__((ext_vector_type(8))) short s16x8;
typedef __attribute__((ext_vector_type(4))) float f32x4;

__device__ __forceinline__ u16 f2bf(float f) {
  unsigned int u = __float_as_uint(f);
  u += 0x7FFFu + ((u >> 16) & 1u);   // RNE
  return (u16)(u >> 16);
}
__device__ __forceinline__ float bf2f(u16 h) {
  return __uint_as_float(((unsigned int)h) << 16);
}

// async global->LDS, 16B per lane; base = lane0's lds ptr, lane i writes base+i*16B.
__device__ __forceinline__ void gload_lds16(const u16* g, u16* l) {
  __builtin_amdgcn_global_load_lds(
      (const __attribute__((address_space(1))) unsigned int*)(g),
      (__attribute__((address_space(3))) unsigned int*)(l), 16, 0, 0);
}

// ---------------- fused fp32 -> bf16 convert: x + all four weights ----------------
__global__ __launch_bounds__(256) void cvt_all(const float* __restrict__ x,
                                               const float* __restrict__ Wq,
                                               const float* __restrict__ Wk,
                                               const float* __restrict__ Wv,
                                               const float* __restrict__ Wo,
                                               u16* __restrict__ xbf,
                                               u16* __restrict__ wbf,
                                               u16* __restrict__ wobf) {
  int blk = blockIdx.x;                // 0..8191
  const float* src;
  u16* dst;
  int i;
  if (blk < 4096) {
    src = x; dst = xbf; i = blk * 256 + threadIdx.x;
  } else {
    int wb = blk - 4096;               // 0..4095
    int sel = wb >> 10;
    src = (sel == 0) ? Wq : (sel == 1) ? Wk : (sel == 2) ? Wv : Wo;
    dst = (sel < 3) ? (wbf + (size_t)sel * 1048576) : wobf;
    i = (wb & 1023) * 256 + threadIdx.x;
  }
  float4 v = reinterpret_cast<const float4*>(src)[i];
  u16x4 o;
  o.x = f2bf(v.x); o.y = f2bf(v.y); o.z = f2bf(v.z); o.w = f2bf(v.w);
  reinterpret_cast<u16x4*>(dst)[i] = o;
}

// ---------------- templated GEMM, BK=64: C[m][n] = sum_k A[m][k]*B[n][k] (B^T) ----------------
__device__ __forceinline__ void store_out(float* p, float v) { *p = v; }
__device__ __forceinline__ void store_out(u16* p, float v) { *p = f2bf(v); }

template <typename OutT, int WM, int WN>
__global__ __launch_bounds__(256) void gemm_bt(const u16* __restrict__ A,
                                               const u16* __restrict__ Bw,
                                               OutT* __restrict__ C, int N, int K) {
  __shared__ u16 As[WM * 2048];
  __shared__ u16 Bs[WN * 2048];
  const int tid = threadIdx.x;
  const int lane = tid & 63;
  const int wave = tid >> 6;
  const int wm = wave >> 1, wn = wave & 1;
  const int lh = lane & 15, quad = lane >> 4;
  const int q8 = quad * 8;
  const int m0 = blockIdx.y * (WM * 32), n0 = blockIdx.x * (WN * 32);
  constexpr int NCH = 4 * (WM + WN);
  constexpr int PER = NCH / 4;

  f32x4 acc[WM][WN];
#pragma unroll
  for (int i = 0; i < WM; ++i)
#pragma unroll
    for (int j = 0; j < WN; ++j) { acc[i][j][0] = 0.f; acc[i][j][1] = 0.f; acc[i][j][2] = 0.f; acc[i][j][3] = 0.f; }

  const int nkt = K >> 6;
  for (int kt = 0; kt < nkt; ++kt) {
    const int kb = kt * 64;
    __syncthreads();
#pragma unroll
    for (int i = 0; i < PER; ++i) {
      const int c = wave * PER + i;
      if (c < 4 * WM) {
        const int rb = c >> 1, kk2 = c & 1;
        gload_lds16(A + (size_t)(m0 + rb * 16 + lh) * K + kb + kk2 * 32 + q8,
                    &As[c * 512 + lane * 8]);
      } else {
        const int cb = c - 4 * WM;
        const int rb = cb >> 1, kk2 = cb & 1;
        gload_lds16(Bw + (size_t)(n0 + rb * 16 + lh) * K + kb + kk2 * 32 + q8,
                    &Bs[cb * 512 + lane * 8]);
      }
    }
    __syncthreads();
#pragma unroll
    for (int kk2 = 0; kk2 < 2; ++kk2) {
      s16x8 af[WM], bf4[WN];
#pragma unroll
      for (int mb = 0; mb < WM; ++mb)
        af[mb] = *reinterpret_cast<const s16x8*>(&As[((wm * WM + mb) * 2 + kk2) * 512 + lane * 8]);
#pragma unroll
      for (int nb = 0; nb < WN; ++nb)
        bf4[nb] = *reinterpret_cast<const s16x8*>(&Bs[((wn * WN + nb) * 2 + kk2) * 512 + lane * 8]);
#pragma unroll
      for (int mb = 0; mb < WM; ++mb)
#pragma unroll
        for (int nb = 0; nb < WN; ++nb)
          acc[mb][nb] = __builtin_amdgcn_mfma_f32_16x16x32_bf16(af[mb], bf4[nb], acc[mb][nb], 0, 0, 0);
    }
  }
#pragma unroll
  for (int mb = 0; mb < WM; ++mb)
#pragma unroll
    for (int nb = 0; nb < WN; ++nb) {
      const int col = n0 + wn * (WN * 16) + nb * 16 + lh;
#pragma unroll
      for (int r = 0; r < 4; ++r) {
        const int row = m0 + wm * (WM * 16) + mb * 16 + quad * 4 + r;
        store_out(&C[(size_t)row * N + col], acc[mb][nb][r]);
      }
    }
}

// ---------------- QKV GEMM (BK=64) with fused RoPE + fused V-transpose epilogue ----------------
// 128x128 tile, N=3072, K=1024, nkt=16. bx<8 Q cols -> rope -> Qs (q/8); bx<16 K cols
// -> rope -> Kb,K2b; bx>=16 V cols -> DIRECT transposed store to Vt (B,H,64,S):
// acc[mb][nb][r] holds 4 consecutive s (r) at fixed d => u16x4 store per (mb,nb).
__global__ __launch_bounds__(256) void qkv_gemm(const u16* __restrict__ A,
                                                const u16* __restrict__ Bw,
                                                u16* __restrict__ Vt,
                                                u16* __restrict__ Qs,
                                                u16* __restrict__ Kb,
                                                u16* __restrict__ K2b) {
  __shared__ u16 As[8192];
  __shared__ u16 Bs[8192];
  const int tid = threadIdx.x;
  const int lane = tid & 63;
  const int wave = tid >> 6;
  const int wm = wave >> 1, wn = wave & 1;
  const int lh = lane & 15, quad = lane >> 4;
  const int q8 = quad * 8;
  const int bx = blockIdx.x;
  const int m0 = blockIdx.y * 128, n0 = bx * 128;
  const int K = 1024;

  f32x4 acc[4][4];
#pragma unroll
  for (int i = 0; i < 4; ++i)
#pragma unroll
    for (int j = 0; j < 4; ++j) { acc[i][j][0] = 0.f; acc[i][j][1] = 0.f; acc[i][j][2] = 0.f; acc[i][j][3] = 0.f; }

  for (int kt = 0; kt < 16; ++kt) {
    const int kb = kt * 64;
    __syncthreads();
#pragma unroll
    for (int i = 0; i < 8; ++i) {
      const int c = wave * 8 + i;   // 0..31: 0-15 A chunks, 16-31 B chunks
      if (c < 16) {
        const int rb = c >> 1, kk2 = c & 1;
        gload_lds16(A + (size_t)(m0 + rb * 16 + lh) * K + kb + kk2 * 32 + q8,
                    &As[c * 512 + lane * 8]);
      } else {
        const int cb = c - 16;
        const int rb = cb >> 1, kk2 = cb & 1;
        gload_lds16(Bw + (size_t)(n0 + rb * 16 + lh) * K + kb + kk2 * 32 + q8,
                    &Bs[cb * 512 + lane * 8]);
      }
    }
    __syncthreads();
#pragma unroll
    for (int kk2 = 0; kk2 < 2; ++kk2) {
      s16x8 af[4], bf4[4];
#pragma unroll
      for (int mb = 0; mb < 4; ++mb)
        af[mb] = *reinterpret_cast<const s16x8*>(&As[((wm * 4 + mb) * 2 + kk2) * 512 + lane * 8]);
#pragma unroll
      for (int nb = 0; nb < 4; ++nb)
        bf4[nb] = *reinterpret_cast<const s16x8*>(&Bs[((wn * 4 + nb) * 2 + kk2) * 512 + lane * 8]);
#pragma unroll
      for (int mb = 0; mb < 4; ++mb)
#pragma unroll
        for (int nb = 0; nb < 4; ++nb)
          acc[mb][nb] = __builtin_amdgcn_mfma_f32_16x16x32_bf16(af[mb], bf4[nb], acc[mb][nb], 0, 0, 0);
    }
  }

  if (bx < 16) {
    const bool isQ = (bx < 8);
#pragma unroll
    for (int nb = 0; nb < 2; ++nb) {
      const int d = nb * 16 + lh;                       // 0..31 (first half of head)
      const float invf = __expf((float)d * -0.2878231366f);  // 10000^(-d/32)
      const int col = n0 + wn * 64 + nb * 16 + lh;
      const int ch = col & 1023;                        // col within Q or K block
      const int h = ch >> 6;
#pragma unroll
      for (int mb = 0; mb < 4; ++mb)
#pragma unroll
        for (int r = 0; r < 4; ++r) {
          const int row = m0 + wm * 64 + mb * 16 + quad * 4 + r;
          const int s = row & 2047, b = row >> 11;
          float ang = (float)s * invf;
          float sv, cv;
          __sincosf(ang, &sv, &cv);
          const float v1 = acc[mb][nb][r], v2 = acc[mb][nb + 2][r];
          const float e0 = v1 * cv - v2 * sv;
          const float e1 = v2 * cv + v1 * sv;
          const size_t ofs = (size_t)((b * 16 + h) * 2048 + s) * 64 + d;
          if (isQ) {
            Qs[ofs]      = f2bf(e0 * 0.125f);
            Qs[ofs + 32] = f2bf(e1 * 0.125f);
          } else {
            Kb[ofs]       = f2bf(e0);
            Kb[ofs + 32]  = f2bf(e1);
            K2b[ofs]      = f2bf(e0 * e0);
            K2b[ofs + 32] = f2bf(e1 * e1);
          }
        }
    }
  } else {
    // V: direct transposed store. col -> (h, d); rows r are 4 consecutive s.
#pragma unroll
    for (int mb = 0; mb < 4; ++mb)
#pragma unroll
      for (int nb = 0; nb < 4; ++nb) {
        const int col = n0 + wn * 64 + nb * 16 + lh;
        const int ch = col & 1023;
        const int h = ch >> 6, d = ch & 63;
        const int row0 = m0 + wm * 64 + mb * 16 + quad * 4;
        const int s0 = row0 & 2047, b = row0 >> 11;
        u16x4 o;
#pragma unroll
        for (int r = 0; r < 4; ++r) o[r] = f2bf(acc[mb][nb][r]);
        *reinterpret_cast<u16x4*>(Vt + (size_t)((b * 16 + h) * 64 + d) * 2048 + s0) = o;
      }
  }
}

// ---------------- flash-style causal amplified attention, fixed-max + split-K ----------------
// LDS double-buffered K/K2 staging, fixed softmax max 8 (exact via shift-invariance),
// Q2 derived in registers. Split-K: qi>=8 FOUR chunks -> Opart; qi 4..7 two -> Opart2;
// qi<4 whole. grid (44, 32): bx<32: qi=15-(bx>>2), chunk=bx&3; bx 32..39: qi=7-((bx-32)>>1),
// half=(bx-32)&1; bx>=40: qi=43-bx.
__global__ __launch_bounds__(256, 2) void attn_kernel(const u16* __restrict__ Qs,
                                                      const u16* __restrict__ Kb,
                                                      const u16* __restrict__ K2b,
                                                      const u16* __restrict__ Vt,
                                                      const float* __restrict__ gate,
                                                      u16* __restrict__ attn,
                                                      float* __restrict__ Opart,
                                                      float* __restrict__ Lpart,
                                                      float* __restrict__ Opart2,
                                                      float* __restrict__ Lpart2) {
  const int bx = blockIdx.x;
  int qi, kt0, kt1, chunk, which;
  bool split;
  if (bx < 32) {
    qi = 15 - (bx >> 2); chunk = bx & 3; split = true; which = 0;
    const int T = 2 * qi + 2;                     // total key tiles
    kt0 = (chunk * T) >> 2;
    kt1 = (((chunk + 1) * T) >> 2) - 1;
  } else if (bx < 40) {
    const int t = bx - 32;
    qi = 7 - (t >> 1); chunk = t & 1; split = true; which = 1;
    const int nk = qi + 1; kt0 = chunk * nk; kt1 = kt0 + nk - 1;
  } else {
    qi = 43 - bx; split = false; which = 0; chunk = 0; kt0 = 0; kt1 = 2 * qi + 1;
  }
  const int bh = blockIdx.y;
  const int tid = threadIdx.x, lane = tid & 63, wave = tid >> 6;
  const int lh = lane & 15, quad = lane >> 4;
  const int b = bh >> 4, h = bh & 15;
  __shared__ u16 stageS[2][8192];   // [K chunks: 0..4095 | K2 chunks: 4096..8191], 512 u16/chunk
  __shared__ u16 Pbuf[4][2][1152];  // per (wave, mb): 16 rows x 72
  const int base = qi * 128 + wave * 32;   // wave's first Q row
  const int q8 = quad * 8;

  auto do_stage = [&](int buf, int kt) {
#pragma unroll
    for (int i = 0; i < 4; ++i) {
      const int c = wave * 4 + i;   // 0..15; t2=c>>3 (0=K,1=K2), f=c&7 = kk*4+nb
      const int t2 = c >> 3, f = c & 7, kk = f >> 2, nb = f & 3;
      const u16* src = (t2 ? K2b : Kb) +
          (size_t)(bh * 2048 + kt * 64 + nb * 16 + lh) * 64 + kk * 32 + q8;
      gload_lds16(src, &stageS[buf][t2 * 4096 + f * 512 + lane * 8]);
    }
  };

  // Q fragments (A-layout): m = lh, k = kk*32 + quad*8 + j ; q/8 pre-scaled in memory.
  s16x8 qf[2][2], q2f[2][2];
#pragma unroll
  for (int mb = 0; mb < 2; ++mb) {
    const size_t qoff = (size_t)(bh * 2048 + base + mb * 16 + lh) * 64 + q8;
#pragma unroll
    for (int kk = 0; kk < 2; ++kk) {
      qf[mb][kk] = *reinterpret_cast<const s16x8*>(Qs + qoff + kk * 32);
#pragma unroll
      for (int j = 0; j < 8; ++j) {
        float f = bf2f((u16)qf[mb][kk][j]);
        q2f[mb][kk][j] = (short)f2bf(f * f * 0.8f);
      }
    }
  }

  f32x4 oacc[2][4];
  float lsum[2][4];
#pragma unroll
  for (int mb = 0; mb < 2; ++mb)
#pragma unroll
    for (int nb = 0; nb < 4; ++nb) { oacc[mb][nb][0] = 0.f; oacc[mb][nb][1] = 0.f; oacc[mb][nb][2] = 0.f; oacc[mb][nb][3] = 0.f; }
#pragma unroll
  for (int mb = 0; mb < 2; ++mb)
#pragma unroll
    for (int r = 0; r < 4; ++r) lsum[mb][r] = 0.f;
  float gw[4];
#pragma unroll
  for (int nb = 0; nb < 4; ++nb) gw[nb] = gate[nb * 16 + lh];

  do_stage(0, kt0);
  __syncthreads();  // drain DMA for first tile

  const int wmaxrow = base + 31;
  for (int kt = kt0; kt <= kt1; ++kt) {
    const int p = (kt - kt0) & 1;
    if (kt < kt1) do_stage(1 - p, kt + 1);  // async prefetch, drained at end barrier

    if (kt * 64 <= wmaxrow) {  // wave-uniform skip of fully-masked tiles
      const u16* Ks = stageS[p];
      f32x4 sacc[2][4];
#pragma unroll
      for (int mb = 0; mb < 2; ++mb)
#pragma unroll
        for (int nb = 0; nb < 4; ++nb) { sacc[mb][nb][0] = -8.f; sacc[mb][nb][1] = -8.f; sacc[mb][nb][2] = -8.f; sacc[mb][nb][3] = -8.f; }
#pragma unroll
      for (int nb = 0; nb < 4; ++nb)
#pragma unroll
        for (int kk = 0; kk < 2; ++kk) {
          s16x8 kf  = *reinterpret_cast<const s16x8*>(&Ks[(kk * 4 + nb) * 512 + lane * 8]);
          s16x8 k2f = *reinterpret_cast<const s16x8*>(&Ks[4096 + (kk * 4 + nb) * 512 + lane * 8]);
#pragma unroll
          for (int mb = 0; mb < 2; ++mb) {
            sacc[mb][nb] = __builtin_amdgcn_mfma_f32_16x16x32_bf16(qf[mb][kk],  kf,  sacc[mb][nb], 0, 0, 0);
            sacc[mb][nb] = __builtin_amdgcn_mfma_f32_16x16x32_bf16(q2f[mb][kk], k2f, sacc[mb][nb], 0, 0, 0);
          }
        }
      // V fragments (global; latency hides under exp/pack, L1-shared by 4 waves)
      s16x8 vf[2][4];
#pragma unroll
      for (int kk = 0; kk < 2; ++kk)
#pragma unroll
        for (int nb = 0; nb < 4; ++nb)
          vf[kk][nb] = *reinterpret_cast<const s16x8*>(
              Vt + (size_t)(bh * 64 + nb * 16 + lh) * 2048 + kt * 64 + kk * 32 + q8);

      if (kt * 64 + 63 > base) {  // tiles overlapping the diagonal: elementwise mask
#pragma unroll
        for (int mb = 0; mb < 2; ++mb)
#pragma unroll
          for (int nb = 0; nb < 4; ++nb) {
            const int colg = kt * 64 + nb * 16 + lh;
#pragma unroll
            for (int r = 0; r < 4; ++r) {
              const int rowg = base + mb * 16 + quad * 4 + r;
              if (colg > rowg) sacc[mb][nb][r] = -1e9f;
            }
          }
      }
      // p = exp(s - 8); per-lane row-sum partials (reduced once after the loop)
#pragma unroll
      for (int mb = 0; mb < 2; ++mb)
#pragma unroll
        for (int nb = 0; nb < 4; ++nb)
#pragma unroll
          for (int r = 0; r < 4; ++r) {
            float pv = __expf(sacc[mb][nb][r]);
            lsum[mb][r] += pv;
            Pbuf[wave][mb][(quad * 4 + r) * 72 + nb * 16 + lh] = f2bf(pv);
          }
      // PV: P through LDS (C-layout -> A-layout), wave-private, no barrier
#pragma unroll
      for (int mb = 0; mb < 2; ++mb)
#pragma unroll
        for (int kk = 0; kk < 2; ++kk) {
          s16x8 pf = *reinterpret_cast<const s16x8*>(&Pbuf[wave][mb][lh * 72 + kk * 32 + q8]);
#pragma unroll
          for (int nb = 0; nb < 4; ++nb)
            oacc[mb][nb] = __builtin_amdgcn_mfma_f32_16x16x32_bf16(pf, vf[kk][nb], oacc[mb][nb], 0, 0, 0);
        }
    }
    __syncthreads();  // all waves done with stageS[p]; prefetch for kt+1 drained
  }
  // reduce row sums across the 16 lanes holding each row
#pragma unroll
  for (int mb = 0; mb < 2; ++mb)
#pragma unroll
    for (int r = 0; r < 4; ++r) {
      float rs = lsum[mb][r];
#pragma unroll
      for (int off = 1; off < 16; off <<= 1) rs += __shfl_xor(rs, off);
      lsum[mb][r] = rs;
    }
  if (split) {
    // unnormalized partials to ws (fp32)
#pragma unroll
    for (int mb = 0; mb < 2; ++mb)
#pragma unroll
      for (int r = 0; r < 4; ++r) {
        const int rowg = base + mb * 16 + quad * 4 + r;
        if (which == 0) {
          const size_t orow = (size_t)chunk * 32768 + bh * 1024 + (rowg - 1024);
          if (lh == 0) Lpart[orow] = lsum[mb][r];
#pragma unroll
          for (int nb = 0; nb < 4; ++nb)
            Opart[orow * 64 + nb * 16 + lh] = oacc[mb][nb][r];
        } else {
          const size_t orow = (size_t)chunk * 16384 + bh * 512 + (rowg - 512);
          if (lh == 0) Lpart2[orow] = lsum[mb][r];
#pragma unroll
          for (int nb = 0; nb < 4; ++nb)
            Opart2[orow * 64 + nb * 16 + lh] = oacc[mb][nb][r];
        }
      }
  } else {
    // finalize: o/l, epilogue o + 0.05*o^2*g[d] (out2==out1 identity)
#pragma unroll
    for (int mb = 0; mb < 2; ++mb)
#pragma unroll
      for (int r = 0; r < 4; ++r) {
        const float invl = 1.0f / lsum[mb][r];
        const int rows = base + mb * 16 + quad * 4 + r;
#pragma unroll
        for (int nb = 0; nb < 4; ++nb) {
          float o = oacc[mb][nb][r] * invl;
          float val = o + 0.05f * o * o * gw[nb];
          attn[(size_t)(b * 2048 + rows) * 1024 + h * 64 + nb * 16 + lh] = f2bf(val);
        }
      }
  }
}

// ---------------- combine split-K partials (rows 512..2047) ----------------
__global__ __launch_bounds__(256) void combine_kernel(const float* __restrict__ Opart,
                                                      const float* __restrict__ Lpart,
                                                      const float* __restrict__ Opart2,
                                                      const float* __restrict__ Lpart2,
                                                      const float* __restrict__ gate,
                                                      u16* __restrict__ attn) {
  int idx = blockIdx.x * 256 + threadIdx.x;   // 0 .. 3145727
  int d = idx & 63;
  int r_all = idx >> 6;
  float o, l;
  int bh, s;
  if (r_all < 32768) {            // rows s >= 1024 (qi >= 8): 4 chunks
    o = Opart[idx] + Opart[idx + 2097152] + Opart[idx + 4194304] + Opart[idx + 6291456];
    l = Lpart[r_all] + Lpart[r_all + 32768] + Lpart[r_all + 65536] + Lpart[r_all + 98304];
    bh = r_all >> 10; s = 1024 + (r_all & 1023);
  } else {                        // rows 512..1023 (qi 4..7): 2 chunks
    const int r2 = r_all - 32768;
    const int i2 = idx - 2097152;
    o = Opart2[i2] + Opart2[i2 + 1048576];
    l = Lpart2[r2] + Lpart2[r2 + 16384];
    bh = r2 >> 9; s = 512 + (r2 & 511);
  }
  o /= l;
  float val = o + 0.05f * o * o * gate[d];
  int b = bh >> 4, h = bh & 15;
  attn[(size_t)(b * 2048 + s) * 1024 + h * 64 + d] = f2bf(val);
}

extern "C" void kernel_launch(void* const* d_in, const int* in_sizes, int n_in,
                              void* d_out, int out_size, void* d_ws, size_t ws_size,
                              hipStream_t stream) {
  (void)in_sizes; (void)n_in; (void)out_size; (void)ws_size;
  const float* x    = (const float*)d_in[0];
  const float* Wq   = (const float*)d_in[1];
  const float* Wk   = (const float*)d_in[2];
  const float* Wv   = (const float*)d_in[3];
  const float* Wo   = (const float*)d_in[4];
  const float* gate = (const float*)d_in[5];

  u16* ws    = (u16*)d_ws;
  u16* xbf   = ws;                    // 4096x1024 bf16 (qkv A input; attn out aliases later)
  u16* wbf   = xbf + 4194304;         // 3072x1024 (Wq|Wk|Wv rows)
  u16* wobf  = wbf + 3145728;         // 1024x1024
  u16* Qsb   = wobf + 1048576;        // (B,H,S,64) q/8
  u16* Kbb   = Qsb + 4194304;         // (B,H,S,64)
  u16* K2bb  = Kbb + 4194304;         // (B,H,S,64)
  u16* Vtb   = K2bb + 4194304;        // (B,H,64,S)  (written directly by qkv epilogue)
  float* Opart  = (float*)(Vtb + 4194304); // 4 x 32 x 1024 x 64 fp32 (33.6 MB)
  float* Lpart  = Opart + 8388608;         // 4 x 32 x 1024 fp32
  float* Opart2 = Lpart + 131072;          // 2 x 32 x 512 x 64 fp32 (8.4 MB)
  float* Lpart2 = Opart2 + 2097152;        // 2 x 32 x 512 fp32
  u16* attnb = xbf;                   // alias: attn out (xbf dead after qkv_gemm)

  cvt_all<<<8192, 256, 0, stream>>>(x, Wq, Wk, Wv, Wo, xbf, wbf, wobf);
  qkv_gemm<<<dim3(24, 32), 256, 0, stream>>>(xbf, wbf, Vtb, Qsb, Kbb, K2bb);
  attn_kernel<<<dim3(44, 32), 256, 0, stream>>>(Qsb, Kbb, K2bb, Vtb, gate, attnb,
                                                Opart, Lpart, Opart2, Lpart2);
  combine_kernel<<<12288, 256, 0, stream>>>(Opart, Lpart, Opart2, Lpart2, gate, attnb);
  gemm_bt<float, 4, 2><<<dim3(16, 32), 256, 0, stream>>>(attnb, wobf, (float*)d_out, 1024, 1024);
}

// Round 12
// 246.665 us; speedup vs baseline: 1.6174x; 1.0446x over previous
//
#include <hip/hip_runtime.h>

typedef unsigned short u16;
typedef __attribute__((ext_vector_type(4))) unsigned short u16x4;
typedef __attribute__((ext_vector_type(8))) unsigned short u16x8;
typedef __attribute__((ext_vector_type(8))) short s16x8;
typedef __attribute__((ext_vector_type(4))) float f32x4;

__device__ __forceinline__ u16 f2bf(float f) {
  unsigned int u = __float_as_uint(f);
  u += 0x7FFFu + ((u >> 16) & 1u);   // RNE
  return (u16)(u >> 16);
}
__device__ __forceinline__ float bf2f(u16 h) {
  return __uint_as_float(((unsigned int)h) << 16);
}

// async global->LDS, 16B per lane; base = lane0's lds ptr, lane i writes base+i*16B.
__device__ __forceinline__ void gload_lds16(const u16* g, u16* l) {
  __builtin_amdgcn_global_load_lds(
      (const __attribute__((address_space(1))) unsigned int*)(g),
      (__attribute__((address_space(3))) unsigned int*)(l), 16, 0, 0);
}

// ---------------- fused fp32 -> bf16 convert: x + all four weights ----------------
__global__ __launch_bounds__(256) void cvt_all(const float* __restrict__ x,
                                               const float* __restrict__ Wq,
                                               const float* __restrict__ Wk,
                                               const float* __restrict__ Wv,
                                               const float* __restrict__ Wo,
                                               u16* __restrict__ xbf,
                                               u16* __restrict__ wbf,
                                               u16* __restrict__ wobf) {
  int blk = blockIdx.x;                // 0..8191
  const float* src;
  u16* dst;
  int i;
  if (blk < 4096) {
    src = x; dst = xbf; i = blk * 256 + threadIdx.x;
  } else {
    int wb = blk - 4096;               // 0..4095
    int sel = wb >> 10;
    src = (sel == 0) ? Wq : (sel == 1) ? Wk : (sel == 2) ? Wv : Wo;
    dst = (sel < 3) ? (wbf + (size_t)sel * 1048576) : wobf;
    i = (wb & 1023) * 256 + threadIdx.x;
  }
  float4 v = reinterpret_cast<const float4*>(src)[i];
  u16x4 o;
  o.x = f2bf(v.x); o.y = f2bf(v.y); o.z = f2bf(v.z); o.w = f2bf(v.w);
  reinterpret_cast<u16x4*>(dst)[i] = o;
}

// ---------------- templated GEMM, BK=32, DOUBLE-BUFFERED staging ----------------
// C[m][n] = sum_k A[m][k]*B[n][k] (B^T). Loop: stage(kt+1) -> compute(kt) -> barrier:
// the DMA drain at the barrier overlaps the whole compute phase (attn-kernel structure).
__device__ __forceinline__ void store_out(float* p, float v) { *p = v; }
__device__ __forceinline__ void store_out(u16* p, float v) { *p = f2bf(v); }

template <typename OutT, int WM, int WN>
__global__ __launch_bounds__(256) void gemm_bt(const u16* __restrict__ A,
                                               const u16* __restrict__ Bw,
                                               OutT* __restrict__ C, int N, int K) {
  __shared__ u16 As[2][WM * 1024];
  __shared__ u16 Bs[2][WN * 1024];
  const int tid = threadIdx.x;
  const int lane = tid & 63;
  const int wave = tid >> 6;
  const int wm = wave >> 1, wn = wave & 1;
  const int lh = lane & 15, quad = lane >> 4;
  const int q8 = quad * 8;
  const int m0 = blockIdx.y * (WM * 32), n0 = blockIdx.x * (WN * 32);
  constexpr int NCH = 2 * (WM + WN);
  constexpr int PER = NCH / 4;

  auto stage = [&](int buf, int kt) {
    const int kb = kt * 32;
#pragma unroll
    for (int i = 0; i < PER; ++i) {
      const int c = wave * PER + i;
      if (c < 2 * WM) {
        gload_lds16(A + (size_t)(m0 + c * 16 + lh) * K + kb + q8,
                    &As[buf][c * 512 + lane * 8]);
      } else {
        const int rb = c - 2 * WM;
        gload_lds16(Bw + (size_t)(n0 + rb * 16 + lh) * K + kb + q8,
                    &Bs[buf][rb * 512 + lane * 8]);
      }
    }
  };

  f32x4 acc[WM][WN];
#pragma unroll
  for (int i = 0; i < WM; ++i)
#pragma unroll
    for (int j = 0; j < WN; ++j) { acc[i][j][0] = 0.f; acc[i][j][1] = 0.f; acc[i][j][2] = 0.f; acc[i][j][3] = 0.f; }

  const int nkt = K >> 5;
  stage(0, 0);
  __syncthreads();  // drain DMA for tile 0
  for (int kt = 0; kt < nkt; ++kt) {
    const int p = kt & 1;
    if (kt < nkt - 1) stage(1 - p, kt + 1);  // prefetch; drained at the end barrier
    s16x8 af[WM], bf4[WN];
#pragma unroll
    for (int mb = 0; mb < WM; ++mb)
      af[mb] = *reinterpret_cast<const s16x8*>(&As[p][(wm * WM + mb) * 512 + lane * 8]);
#pragma unroll
    for (int nb = 0; nb < WN; ++nb)
      bf4[nb] = *reinterpret_cast<const s16x8*>(&Bs[p][(wn * WN + nb) * 512 + lane * 8]);
#pragma unroll
    for (int mb = 0; mb < WM; ++mb)
#pragma unroll
      for (int nb = 0; nb < WN; ++nb)
        acc[mb][nb] = __builtin_amdgcn_mfma_f32_16x16x32_bf16(af[mb], bf4[nb], acc[mb][nb], 0, 0, 0);
    __syncthreads();  // all waves done reading buf p; prefetch into 1-p drained
  }
#pragma unroll
  for (int mb = 0; mb < WM; ++mb)
#pragma unroll
    for (int nb = 0; nb < WN; ++nb) {
      const int col = n0 + wn * (WN * 16) + nb * 16 + lh;
#pragma unroll
      for (int r = 0; r < 4; ++r) {
        const int row = m0 + wm * (WM * 16) + mb * 16 + quad * 4 + r;
        store_out(&C[(size_t)row * N + col], acc[mb][nb][r]);
      }
    }
}

// ---------------- QKV GEMM (BK=32, double-buffered) + fused RoPE + V-transpose ----------------
// 128x128 tile, N=3072, K=1024, nkt=32. bx<8 Q cols -> rope -> Qs (q/8); bx<16 K cols
// -> rope -> Kb,K2b; bx>=16 V cols -> direct transposed store to Vt (B,H,64,S).
__global__ __launch_bounds__(256) void qkv_gemm(const u16* __restrict__ A,
                                                const u16* __restrict__ Bw,
                                                u16* __restrict__ Vt,
                                                u16* __restrict__ Qs,
                                                u16* __restrict__ Kb,
                                                u16* __restrict__ K2b) {
  __shared__ u16 As[2][4096];
  __shared__ u16 Bs[2][4096];
  const int tid = threadIdx.x;
  const int lane = tid & 63;
  const int wave = tid >> 6;
  const int wm = wave >> 1, wn = wave & 1;
  const int lh = lane & 15, quad = lane >> 4;
  const int q8 = quad * 8;
  const int bx = blockIdx.x;
  const int m0 = blockIdx.y * 128, n0 = bx * 128;
  const int K = 1024;

  auto stage = [&](int buf, int kt) {
    const int kb = kt * 32;
#pragma unroll
    for (int i = 0; i < 4; ++i) {
      const int c = wave * 4 + i;  // 0..15: 0-7 A chunks, 8-15 B chunks
      if (c < 8) {
        gload_lds16(A + (size_t)(m0 + c * 16 + lh) * K + kb + q8,
                    &As[buf][c * 512 + lane * 8]);
      } else {
        const int rb = c - 8;
        gload_lds16(Bw + (size_t)(n0 + rb * 16 + lh) * K + kb + q8,
                    &Bs[buf][rb * 512 + lane * 8]);
      }
    }
  };

  f32x4 acc[4][4];
#pragma unroll
  for (int i = 0; i < 4; ++i)
#pragma unroll
    for (int j = 0; j < 4; ++j) { acc[i][j][0] = 0.f; acc[i][j][1] = 0.f; acc[i][j][2] = 0.f; acc[i][j][3] = 0.f; }

  stage(0, 0);
  __syncthreads();
  for (int kt = 0; kt < 32; ++kt) {
    const int p = kt & 1;
    if (kt < 31) stage(1 - p, kt + 1);
    s16x8 af[4], bf4[4];
#pragma unroll
    for (int mb = 0; mb < 4; ++mb)
      af[mb] = *reinterpret_cast<const s16x8*>(&As[p][(wm * 4 + mb) * 512 + lane * 8]);
#pragma unroll
    for (int nb = 0; nb < 4; ++nb)
      bf4[nb] = *reinterpret_cast<const s16x8*>(&Bs[p][(wn * 4 + nb) * 512 + lane * 8]);
#pragma unroll
    for (int mb = 0; mb < 4; ++mb)
#pragma unroll
      for (int nb = 0; nb < 4; ++nb)
        acc[mb][nb] = __builtin_amdgcn_mfma_f32_16x16x32_bf16(af[mb], bf4[nb], acc[mb][nb], 0, 0, 0);
    __syncthreads();
  }

  if (bx < 16) {
    const bool isQ = (bx < 8);
#pragma unroll
    for (int nb = 0; nb < 2; ++nb) {
      const int d = nb * 16 + lh;                       // 0..31 (first half of head)
      const float invf = __expf((float)d * -0.2878231366f);  // 10000^(-d/32)
      const int col = n0 + wn * 64 + nb * 16 + lh;
      const int ch = col & 1023;                        // col within Q or K block
      const int h = ch >> 6;
#pragma unroll
      for (int mb = 0; mb < 4; ++mb)
#pragma unroll
        for (int r = 0; r < 4; ++r) {
          const int row = m0 + wm * 64 + mb * 16 + quad * 4 + r;
          const int s = row & 2047, b = row >> 11;
          float ang = (float)s * invf;
          float sv, cv;
          __sincosf(ang, &sv, &cv);
          const float v1 = acc[mb][nb][r], v2 = acc[mb][nb + 2][r];
          const float e0 = v1 * cv - v2 * sv;
          const float e1 = v2 * cv + v1 * sv;
          const size_t ofs = (size_t)((b * 16 + h) * 2048 + s) * 64 + d;
          if (isQ) {
            Qs[ofs]      = f2bf(e0 * 0.125f);
            Qs[ofs + 32] = f2bf(e1 * 0.125f);
          } else {
            Kb[ofs]       = f2bf(e0);
            Kb[ofs + 32]  = f2bf(e1);
            K2b[ofs]      = f2bf(e0 * e0);
            K2b[ofs + 32] = f2bf(e1 * e1);
          }
        }
    }
  } else {
    // V: direct transposed store. col -> (h, d); rows r are 4 consecutive s.
#pragma unroll
    for (int mb = 0; mb < 4; ++mb)
#pragma unroll
      for (int nb = 0; nb < 4; ++nb) {
        const int col = n0 + wn * 64 + nb * 16 + lh;
        const int ch = col & 1023;
        const int h = ch >> 6, d = ch & 63;
        const int row0 = m0 + wm * 64 + mb * 16 + quad * 4;
        const int s0 = row0 & 2047, b = row0 >> 11;
        u16x4 o;
#pragma unroll
        for (int r = 0; r < 4; ++r) o[r] = f2bf(acc[mb][nb][r]);
        *reinterpret_cast<u16x4*>(Vt + (size_t)((b * 16 + h) * 64 + d) * 2048 + s0) = o;
      }
  }
}

// ---------------- flash-style causal amplified attention, fixed-max + split-K ----------------
// LDS double-buffered K/K2 staging, fixed softmax max 8 (exact via shift-invariance),
// Q2 derived in registers. Split-K: qi>=8 FOUR chunks -> Opart; qi 4..7 two -> Opart2;
// qi<4 whole. grid (44, 32): bx<32: qi=15-(bx>>2), chunk=bx&3; bx 32..39: qi=7-((bx-32)>>1),
// half=(bx-32)&1; bx>=40: qi=43-bx.
__global__ __launch_bounds__(256, 2) void attn_kernel(const u16* __restrict__ Qs,
                                                      const u16* __restrict__ Kb,
                                                      const u16* __restrict__ K2b,
                                                      const u16* __restrict__ Vt,
                                                      const float* __restrict__ gate,
                                                      u16* __restrict__ attn,
                                                      float* __restrict__ Opart,
                                                      float* __restrict__ Lpart,
                                                      float* __restrict__ Opart2,
                                                      float* __restrict__ Lpart2) {
  const int bx = blockIdx.x;
  int qi, kt0, kt1, chunk, which;
  bool split;
  if (bx < 32) {
    qi = 15 - (bx >> 2); chunk = bx & 3; split = true; which = 0;
    const int T = 2 * qi + 2;                     // total key tiles
    kt0 = (chunk * T) >> 2;
    kt1 = (((chunk + 1) * T) >> 2) - 1;
  } else if (bx < 40) {
    const int t = bx - 32;
    qi = 7 - (t >> 1); chunk = t & 1; split = true; which = 1;
    const int nk = qi + 1; kt0 = chunk * nk; kt1 = kt0 + nk - 1;
  } else {
    qi = 43 - bx; split = false; which = 0; chunk = 0; kt0 = 0; kt1 = 2 * qi + 1;
  }
  const int bh = blockIdx.y;
  const int tid = threadIdx.x, lane = tid & 63, wave = tid >> 6;
  const int lh = lane & 15, quad = lane >> 4;
  const int b = bh >> 4, h = bh & 15;
  __shared__ u16 stageS[2][8192];   // [K chunks: 0..4095 | K2 chunks: 4096..8191], 512 u16/chunk
  __shared__ u16 Pbuf[4][2][1152];  // per (wave, mb): 16 rows x 72
  const int base = qi * 128 + wave * 32;   // wave's first Q row
  const int q8 = quad * 8;

  auto do_stage = [&](int buf, int kt) {
#pragma unroll
    for (int i = 0; i < 4; ++i) {
      const int c = wave * 4 + i;   // 0..15; t2=c>>3 (0=K,1=K2), f=c&7 = kk*4+nb
      const int t2 = c >> 3, f = c & 7, kk = f >> 2, nb = f & 3;
      const u16* src = (t2 ? K2b : Kb) +
          (size_t)(bh * 2048 + kt * 64 + nb * 16 + lh) * 64 + kk * 32 + q8;
      gload_lds16(src, &stageS[buf][t2 * 4096 + f * 512 + lane * 8]);
    }
  };

  // Q fragments (A-layout): m = lh, k = kk*32 + quad*8 + j ; q/8 pre-scaled in memory.
  s16x8 qf[2][2], q2f[2][2];
#pragma unroll
  for (int mb = 0; mb < 2; ++mb) {
    const size_t qoff = (size_t)(bh * 2048 + base + mb * 16 + lh) * 64 + q8;
#pragma unroll
    for (int kk = 0; kk < 2; ++kk) {
      qf[mb][kk] = *reinterpret_cast<const s16x8*>(Qs + qoff + kk * 32);
#pragma unroll
      for (int j = 0; j < 8; ++j) {
        float f = bf2f((u16)qf[mb][kk][j]);
        q2f[mb][kk][j] = (short)f2bf(f * f * 0.8f);
      }
    }
  }

  f32x4 oacc[2][4];
  float lsum[2][4];
#pragma unroll
  for (int mb = 0; mb < 2; ++mb)
#pragma unroll
    for (int nb = 0; nb < 4; ++nb) { oacc[mb][nb][0] = 0.f; oacc[mb][nb][1] = 0.f; oacc[mb][nb][2] = 0.f; oacc[mb][nb][3] = 0.f; }
#pragma unroll
  for (int mb = 0; mb < 2; ++mb)
#pragma unroll
    for (int r = 0; r < 4; ++r) lsum[mb][r] = 0.f;
  float gw[4];
#pragma unroll
  for (int nb = 0; nb < 4; ++nb) gw[nb] = gate[nb * 16 + lh];

  do_stage(0, kt0);
  __syncthreads();  // drain DMA for first tile

  const int wmaxrow = base + 31;
  for (int kt = kt0; kt <= kt1; ++kt) {
    const int p = (kt - kt0) & 1;
    if (kt < kt1) do_stage(1 - p, kt + 1);  // async prefetch, drained at end barrier

    if (kt * 64 <= wmaxrow) {  // wave-uniform skip of fully-masked tiles
      const u16* Ks = stageS[p];
      f32x4 sacc[2][4];
#pragma unroll
      for (int mb = 0; mb < 2; ++mb)
#pragma unroll
        for (int nb = 0; nb < 4; ++nb) { sacc[mb][nb][0] = -8.f; sacc[mb][nb][1] = -8.f; sacc[mb][nb][2] = -8.f; sacc[mb][nb][3] = -8.f; }
#pragma unroll
      for (int nb = 0; nb < 4; ++nb)
#pragma unroll
        for (int kk = 0; kk < 2; ++kk) {
          s16x8 kf  = *reinterpret_cast<const s16x8*>(&Ks[(kk * 4 + nb) * 512 + lane * 8]);
          s16x8 k2f = *reinterpret_cast<const s16x8*>(&Ks[4096 + (kk * 4 + nb) * 512 + lane * 8]);
#pragma unroll
          for (int mb = 0; mb < 2; ++mb) {
            sacc[mb][nb] = __builtin_amdgcn_mfma_f32_16x16x32_bf16(qf[mb][kk],  kf,  sacc[mb][nb], 0, 0, 0);
            sacc[mb][nb] = __builtin_amdgcn_mfma_f32_16x16x32_bf16(q2f[mb][kk], k2f, sacc[mb][nb], 0, 0, 0);
          }
        }
      // V fragments (global; latency hides under exp/pack, L1-shared by 4 waves)
      s16x8 vf[2][4];
#pragma unroll
      for (int kk = 0; kk < 2; ++kk)
#pragma unroll
        for (int nb = 0; nb < 4; ++nb)
          vf[kk][nb] = *reinterpret_cast<const s16x8*>(
              Vt + (size_t)(bh * 64 + nb * 16 + lh) * 2048 + kt * 64 + kk * 32 + q8);

      if (kt * 64 + 63 > base) {  // tiles overlapping the diagonal: elementwise mask
#pragma unroll
        for (int mb = 0; mb < 2; ++mb)
#pragma unroll
          for (int nb = 0; nb < 4; ++nb) {
            const int colg = kt * 64 + nb * 16 + lh;
#pragma unroll
            for (int r = 0; r < 4; ++r) {
              const int rowg = base + mb * 16 + quad * 4 + r;
              if (colg > rowg) sacc[mb][nb][r] = -1e9f;
            }
          }
      }
      // p = exp(s - 8); per-lane row-sum partials (reduced once after the loop)
#pragma unroll
      for (int mb = 0; mb < 2; ++mb)
#pragma unroll
        for (int nb = 0; nb < 4; ++nb)
#pragma unroll
          for (int r = 0; r < 4; ++r) {
            float pv = __expf(sacc[mb][nb][r]);
            lsum[mb][r] += pv;
            Pbuf[wave][mb][(quad * 4 + r) * 72 + nb * 16 + lh] = f2bf(pv);
          }
      // PV: P through LDS (C-layout -> A-layout), wave-private, no barrier
#pragma unroll
      for (int mb = 0; mb < 2; ++mb)
#pragma unroll
        for (int kk = 0; kk < 2; ++kk) {
          s16x8 pf = *reinterpret_cast<const s16x8*>(&Pbuf[wave][mb][lh * 72 + kk * 32 + q8]);
#pragma unroll
          for (int nb = 0; nb < 4; ++nb)
            oacc[mb][nb] = __builtin_amdgcn_mfma_f32_16x16x32_bf16(pf, vf[kk][nb], oacc[mb][nb], 0, 0, 0);
        }
    }
    __syncthreads();  // all waves done with stageS[p]; prefetch for kt+1 drained
  }
  // reduce row sums across the 16 lanes holding each row
#pragma unroll
  for (int mb = 0; mb < 2; ++mb)
#pragma unroll
    for (int r = 0; r < 4; ++r) {
      float rs = lsum[mb][r];
#pragma unroll
      for (int off = 1; off < 16; off <<= 1) rs += __shfl_xor(rs, off);
      lsum[mb][r] = rs;
    }
  if (split) {
    // unnormalized partials to ws (fp32)
#pragma unroll
    for (int mb = 0; mb < 2; ++mb)
#pragma unroll
      for (int r = 0; r < 4; ++r) {
        const int rowg = base + mb * 16 + quad * 4 + r;
        if (which == 0) {
          const size_t orow = (size_t)chunk * 32768 + bh * 1024 + (rowg - 1024);
          if (lh == 0) Lpart[orow] = lsum[mb][r];
#pragma unroll
          for (int nb = 0; nb < 4; ++nb)
            Opart[orow * 64 + nb * 16 + lh] = oacc[mb][nb][r];
        } else {
          const size_t orow = (size_t)chunk * 16384 + bh * 512 + (rowg - 512);
          if (lh == 0) Lpart2[orow] = lsum[mb][r];
#pragma unroll
          for (int nb = 0; nb < 4; ++nb)
            Opart2[orow * 64 + nb * 16 + lh] = oacc[mb][nb][r];
        }
      }
  } else {
    // finalize: o/l, epilogue o + 0.05*o^2*g[d] (out2==out1 identity)
#pragma unroll
    for (int mb = 0; mb < 2; ++mb)
#pragma unroll
      for (int r = 0; r < 4; ++r) {
        const float invl = 1.0f / lsum[mb][r];
        const int rows = base + mb * 16 + quad * 4 + r;
#pragma unroll
        for (int nb = 0; nb < 4; ++nb) {
          float o = oacc[mb][nb][r] * invl;
          float val = o + 0.05f * o * o * gw[nb];
          attn[(size_t)(b * 2048 + rows) * 1024 + h * 64 + nb * 16 + lh] = f2bf(val);
        }
      }
  }
}

// ---------------- combine split-K partials (rows 512..2047) ----------------
__global__ __launch_bounds__(256) void combine_kernel(const float* __restrict__ Opart,
                                                      const float* __restrict__ Lpart,
                                                      const float* __restrict__ Opart2,
                                                      const float* __restrict__ Lpart2,
                                                      const float* __restrict__ gate,
                                                      u16* __restrict__ attn) {
  int idx = blockIdx.x * 256 + threadIdx.x;   // 0 .. 3145727
  int d = idx & 63;
  int r_all = idx >> 6;
  float o, l;
  int bh, s;
  if (r_all < 32768) {            // rows s >= 1024 (qi >= 8): 4 chunks
    o = Opart[idx] + Opart[idx + 2097152] + Opart[idx + 4194304] + Opart[idx + 6291456];
    l = Lpart[r_all] + Lpart[r_all + 32768] + Lpart[r_all + 65536] + Lpart[r_all + 98304];
    bh = r_all >> 10; s = 1024 + (r_all & 1023);
  } else {                        // rows 512..1023 (qi 4..7): 2 chunks
    const int r2 = r_all - 32768;
    const int i2 = idx - 2097152;
    o = Opart2[i2] + Opart2[i2 + 1048576];
    l = Lpart2[r2] + Lpart2[r2 + 16384];
    bh = r2 >> 9; s = 512 + (r2 & 511);
  }
  o /= l;
  float val = o + 0.05f * o * o * gate[d];
  int b = bh >> 4, h = bh & 15;
  attn[(size_t)(b * 2048 + s) * 1024 + h * 64 + d] = f2bf(val);
}

extern "C" void kernel_launch(void* const* d_in, const int* in_sizes, int n_in,
                              void* d_out, int out_size, void* d_ws, size_t ws_size,
                              hipStream_t stream) {
  (void)in_sizes; (void)n_in; (void)out_size; (void)ws_size;
  const float* x    = (const float*)d_in[0];
  const float* Wq   = (const float*)d_in[1];
  const float* Wk   = (const float*)d_in[2];
  const float* Wv   = (const float*)d_in[3];
  const float* Wo   = (const float*)d_in[4];
  const float* gate = (const float*)d_in[5];

  u16* ws    = (u16*)d_ws;
  u16* xbf   = ws;                    // 4096x1024 bf16 (qkv A input; attn out aliases later)
  u16* wbf   = xbf + 4194304;         // 3072x1024 (Wq|Wk|Wv rows)
  u16* wobf  = wbf + 3145728;         // 1024x1024
  u16* Qsb   = wobf + 1048576;        // (B,H,S,64) q/8
  u16* Kbb   = Qsb + 4194304;         // (B,H,S,64)
  u16* K2bb  = Kbb + 4194304;         // (B,H,S,64)
  u16* Vtb   = K2bb + 4194304;        // (B,H,64,S)  (written directly by qkv epilogue)
  float* Opart  = (float*)(Vtb + 4194304); // 4 x 32 x 1024 x 64 fp32 (33.6 MB)
  float* Lpart  = Opart + 8388608;         // 4 x 32 x 1024 fp32
  float* Opart2 = Lpart + 131072;          // 2 x 32 x 512 x 64 fp32 (8.4 MB)
  float* Lpart2 = Opart2 + 2097152;        // 2 x 32 x 512 fp32
  u16* attnb = xbf;                   // alias: attn out (xbf dead after qkv_gemm)

  cvt_all<<<8192, 256, 0, stream>>>(x, Wq, Wk, Wv, Wo, xbf, wbf, wobf);
  qkv_gemm<<<dim3(24, 32), 256, 0, stream>>>(xbf, wbf, Vtb, Qsb, Kbb, K2bb);
  attn_kernel<<<dim3(44, 32), 256, 0, stream>>>(Qsb, Kbb, K2bb, Vtb, gate, attnb,
                                                Opart, Lpart, Opart2, Lpart2);
  combine_kernel<<<12288, 256, 0, stream>>>(Opart, Lpart, Opart2, Lpart2, gate, attnb);
  gemm_bt<float, 4, 2><<<dim3(16, 32), 256, 0, stream>>>(attnb, wobf, (float*)d_out, 1024, 1024);
}